// Round 6
// baseline (1551.727 us; speedup 1.0000x reference)
//
#include <hip/hip_runtime.h>
#include <hip/hip_bf16.h>

using u32 = unsigned int;
using u64 = unsigned long long;

// f32 threshold exactly as the reference elementwise ops: rs = 1/sqrt(1+eps),
// s = g*rs, t = z*s + b, all separately rounded f32 (no FMA).
__device__ __forceinline__ float bn_t32(float z, float g, float b){
  const float rs = __fdiv_rn(1.0f, __fsqrt_rn((float)(1.0 + 1e-5)));
  float s = __fmul_rn(g, rs);
  return __fadd_rn(__fmul_rn(z, s), b);
}

// ---------------------------------------------------------------------------
// Ternary weight pack: conv weights [COUT][CIN][3][3] -> wp[tap][ciw][COUT][2]
// plane 0 (A) bit j = (w != 0), plane 1 (S) bit j = (w > 0)
// ---------------------------------------------------------------------------
__global__ void pack_w_k(const float* __restrict__ w, u32* __restrict__ wp,
                         int CIN, int COUT){
  int CW = CIN >> 5;
  int total = COUT * 9 * CW;
  int idx = blockIdx.x * 256 + threadIdx.x;
  if (idx >= total) return;
  int co = idx % COUT; int t = idx / COUT;
  int ciw = t % CW; int tap = t / CW;
  u32 a = 0, s = 0;
  for (int j = 0; j < 32; j++){
    float v = w[(co*CIN + (ciw*32 + j))*9 + tap];
    a |= (v != 0.f ? 1u : 0u) << j;
    s |= (v >  0.f ? 1u : 0u) << j;
  }
  wp[idx*2]   = a;
  wp[idx*2+1] = s;
}

// FC weight pack: w [COUT][K] -> wp[kw][COUT][2]
__global__ void pack_fc_k(const float* __restrict__ w, u32* __restrict__ wp,
                          int K, int COUT){
  int KW = K >> 5;
  int total = COUT * KW;
  int idx = blockIdx.x * 256 + threadIdx.x;
  if (idx >= total) return;
  int co = idx % COUT; int kw = idx / COUT;
  u32 a = 0, s = 0;
  for (int j = 0; j < 32; j++){
    float v = w[co*K + kw*32 + j];
    a |= (v != 0.f ? 1u : 0u) << j;
    s |= (v >  0.f ? 1u : 0u) << j;
  }
  wp[(kw*COUT + co)*2]   = a;
  wp[(kw*COUT + co)*2+1] = s;
}

// fc1 weight pack, K permuted to our [y][x][cw] layout: k = c*16 + y*4 + x
__global__ void pack_fc1_k(const float* __restrict__ w, u32* __restrict__ wp){
  int idx = blockIdx.x * 256 + threadIdx.x;   // 1024*256
  int co = idx % 1024; int kw = idx / 1024;
  int px = kw >> 4, cw = kw & 15;
  u32 a = 0, s = 0;
  for (int j = 0; j < 32; j++){
    float v = w[co*8192 + (cw*32 + j)*16 + px];
    a |= (v != 0.f ? 1u : 0u) << j;
    s |= (v >  0.f ? 1u : 0u) << j;
  }
  wp[(kw*1024 + co)*2]   = a;
  wp[(kw*1024 + co)*2+1] = s;
}

// ---------------------------------------------------------------------------
// conv1: f32, tap-major (9 shifted 1x1 convs, ci-inner), + c1b, f32 bn,
// ternary double-ballot -> s1 [128][32][32][4][2]
// ---------------------------------------------------------------------------
__global__ __launch_bounds__(256) void conv1_k(
    const float* __restrict__ x, const float* __restrict__ w1,
    const float* __restrict__ c1b,
    const float* __restrict__ g1, const float* __restrict__ bt1,
    u32* __restrict__ s1p){
  int tid = threadIdx.x; int lane = tid & 63; int wv = tid >> 6;
  int wid = blockIdx.x*4 + wv;                 // 128*32*32*2 waves
  int cg = wid & 1; int p = wid >> 1;
  int xx = p & 31; p >>= 5; int yy = p & 31; int n = p >> 5;
  int co = cg*64 + lane;
  float acc = 0.f;
  for (int tap = 0; tap < 9; tap++){
    int dy = tap/3 - 1, dx = tap%3 - 1;
    int iy = yy + dy, ix = xx + dx;
    if (iy < 0 || iy > 31 || ix < 0 || ix > 31) continue;
    float pt = 0.f;
    for (int ci = 0; ci < 3; ci++){
      float wv_ = w1[(co*3 + ci)*9 + tap];
      float sg = (wv_ > 0.f) ? 1.f : ((wv_ < 0.f) ? -1.f : 0.f);
      pt = __fadd_rn(pt, __fmul_rn(sg, x[((n*3 + ci)*32 + iy)*32 + ix]));
    }
    acc = __fadd_rn(acc, pt);
  }
  float v = __fadd_rn(acc, c1b[co]);
  float t = bn_t32(v, g1[co], bt1[co]);
  u64 mP = __ballot(t > 0.f);
  u64 mN = __ballot(t < 0.f);
  if (lane == 0){
    int o = (((n*32 + yy)*32 + xx)*4 + cg*2)*2;
    s1p[o]   = (u32)(mP | mN);       // A plane, low word
    s1p[o+1] = (u32)mP;              // S plane, low word
    s1p[o+2] = (u32)((mP | mN) >> 32);
    s1p[o+3] = (u32)(mP >> 32);
  }
}

// ---------------------------------------------------------------------------
// Ternary bconv (+optional pool) + f32 bn + ternary double-ballot.
// A: [N][H][W][CW][2]; Wp: [9][CW][COUT][2]; Op: [N][HO][WO][COUT/32][2]
// ---------------------------------------------------------------------------
template<int CW, int COUT, int H, int W, int POOL>
__global__ __launch_bounds__(256) void bconv_k(
    const u32* __restrict__ A, const u32* __restrict__ Wp,
    const float* __restrict__ g, const float* __restrict__ bt,
    u32* __restrict__ Op){
  constexpr int CG = COUT / 64;
  constexpr int HO = POOL ? H/2 : H;
  constexpr int WO = POOL ? W/2 : W;
  constexpr int PX = POOL ? 2 : 1;
  int tid = threadIdx.x; int lane = tid & 63; int wv = tid >> 6;
  int wid = blockIdx.x*4 + wv;
  int cg = wid % CG; int r = wid / CG;
  int ox = r % WO; r /= WO; int oy = r % HO; int n = r / HO;
  int co = cg*64 + lane;

  int zacc[PX*PX];
  #pragma unroll
  for (int i = 0; i < PX*PX; i++) zacc[i] = 0;
  int iy0 = POOL ? oy*2 : oy;
  int ix0 = POOL ? ox*2 : ox;

  #pragma unroll
  for (int tap = 0; tap < 9; tap++){
    int dy = tap/3 - 1, dx = tap%3 - 1;
    u32 wA[CW], wS[CW];
    #pragma unroll
    for (int cw = 0; cw < CW; cw++){
      uint2 wpair = reinterpret_cast<const uint2*>(Wp)[(tap*CW + cw)*COUT + co];
      wA[cw] = wpair.x; wS[cw] = wpair.y;
    }
    #pragma unroll
    for (int py = 0; py < PX; py++){
      int y = iy0 + py + dy; if (y < 0 || y >= H) continue;
      #pragma unroll
      for (int px = 0; px < PX; px++){
        int x = ix0 + px + dx; if (x < 0 || x >= W) continue;
        const uint2* ap = reinterpret_cast<const uint2*>(
            &A[((((size_t)n*H + y)*W + x)*CW)*2]);
        int zz = 0;
        #pragma unroll
        for (int cw = 0; cw < CW; cw++){
          uint2 av = ap[cw];
          u32 v = av.x & wA[cw];
          u32 d = v & (av.y ^ wS[cw]);
          zz += __popc(v) - 2*__popc(d);
        }
        zacc[py*PX+px] += zz;
      }
    }
  }
  int zbest = zacc[0];
  #pragma unroll
  for (int i = 1; i < PX*PX; i++) zbest = max(zbest, zacc[i]);
  float t = bn_t32((float)zbest, g[co], bt[co]);
  u64 mP = __ballot(t > 0.f);
  u64 mN = __ballot(t < 0.f);
  if (lane == 0){
    int o = ((((n*HO) + oy)*WO + ox)*(COUT/32) + cg*2)*2;
    Op[o]   = (u32)(mP | mN);
    Op[o+1] = (u32)mP;
    Op[o+2] = (u32)((mP | mN) >> 32);
    Op[o+3] = (u32)(mP >> 32);
  }
}

// ---------------------------------------------------------------------------
// Ternary FC + f32 bn + ternary ballot. A:[128][KW][2], Wp:[KW][1024][2],
// Op:[128][32][2].
// ---------------------------------------------------------------------------
template<int KW>
__global__ __launch_bounds__(256) void fcb_k(
    const u32* __restrict__ A, const u32* __restrict__ Wp,
    const float* __restrict__ fb,
    const float* __restrict__ g, const float* __restrict__ bt,
    u32* __restrict__ Op){
  int tid = threadIdx.x; int lane = tid & 63; int wv = tid >> 6;
  int wid = blockIdx.x*4 + wv;          // 128*16 waves
  int og = wid & 15; int n = wid >> 4;
  int o = og*64 + lane;
  const uint2* a = reinterpret_cast<const uint2*>(&A[(size_t)n*KW*2]);
  int z = 0;
  #pragma unroll 8
  for (int kw = 0; kw < KW; kw++){
    uint2 av = a[kw];
    uint2 wv_ = reinterpret_cast<const uint2*>(Wp)[kw*1024 + o];
    u32 v = av.x & wv_.x;
    u32 d = v & (av.y ^ wv_.y);
    z += __popc(v) - 2*__popc(d);
  }
  float vv = __fadd_rn((float)z, fb[o]);
  float t = bn_t32(vv, g[o], bt[o]);
  u64 mP = __ballot(t > 0.f);
  u64 mN = __ballot(t < 0.f);
  if (lane == 0){
    int ob = (n*32 + og*2)*2;
    Op[ob]   = (u32)(mP | mN);
    Op[ob+1] = (u32)mP;
    Op[ob+2] = (u32)((mP | mN) >> 32);
    Op[ob+3] = (u32)(mP >> 32);
  }
}

// fc3 (10 outputs) + bn + log_softmax (f64 smooth tail) -> f32 out [128][10]
__global__ void fc3_k(const u32* __restrict__ A, const u32* __restrict__ Wp,
                      const float* __restrict__ fb,
                      const float* __restrict__ g,
                      const float* __restrict__ bt,
                      float* __restrict__ out){
  int n = blockIdx.x; int lane = threadIdx.x;   // blockDim = 64
  __shared__ double ls[10];
  double t = 0.0;
  if (lane < 10){
    const uint2* a = reinterpret_cast<const uint2*>(&A[(size_t)n*32*2]);
    int z = 0;
    for (int kw = 0; kw < 32; kw++){
      uint2 av = a[kw];
      uint2 wv_ = reinterpret_cast<const uint2*>(Wp)[kw*10 + lane];
      u32 v = av.x & wv_.x;
      u32 d = v & (av.y ^ wv_.y);
      z += __popc(v) - 2*__popc(d);
    }
    float vv = __fadd_rn((float)z, fb[lane]);
    float tf = bn_t32(vv, g[lane], bt[lane]);
    t = (double)tf;
    ls[lane] = t;
  }
  __syncthreads();
  if (lane < 10){
    double m = -1e300;
    for (int j = 0; j < 10; j++) m = fmax(m, ls[j]);
    double sum = 0.0;
    for (int j = 0; j < 10; j++) sum += exp(ls[j] - m);
    double r = t - m - log(sum);
    out[n*10 + lane] = (float)r;
  }
}

extern "C" void kernel_launch(void* const* d_in, const int* in_sizes, int n_in,
                              void* d_out, int out_size, void* d_ws, size_t ws_size,
                              hipStream_t stream){
  auto f = [&](int i){ return (const float*)d_in[i]; };
  const float *x  = f(0),  *w1 = f(1),  *c1b = f(2),
    *w2 = f(3),  *w3 = f(4),  *w4 = f(5),  *w5 = f(6),  *w6 = f(7),
    *fw1 = f(8), *fb1 = f(9), *fw2 = f(10), *fb2 = f(11),
    *fw3 = f(12), *fb3 = f(13),
    *g1 = f(14), *bt1 = f(15), *g2 = f(16), *bt2 = f(17),
    *g3 = f(18), *bt3 = f(19), *g4 = f(20), *bt4 = f(21),
    *g5 = f(22), *bt5 = f(23), *g6 = f(24), *bt6 = f(25),
    *gf1 = f(26), *btf1 = f(27), *gf2 = f(28), *btf2 = f(29),
    *gf3 = f(30), *btf3 = f(31);

  u32* W = (u32*)d_ws;
  size_t off = 0;
  auto alloc = [&](size_t words){ u32* p = W + off; off += (words + 63) & ~(size_t)63; return p; };
  // all sizes doubled for the two planes
  u32 *wp2 = alloc(2*9*4*128),  *wp3 = alloc(2*9*4*256), *wp4 = alloc(2*9*8*256),
      *wp5 = alloc(2*9*8*512),  *wp6 = alloc(2*9*16*512),
      *fw1p = alloc(2*256*1024), *fw2p = alloc(2*32*1024), *fw3p = alloc(2*32*10),
      *s1 = alloc(2*128*32*32*4), *s2 = alloc(2*128*16*16*4), *s3 = alloc(2*128*16*16*8),
      *s4 = alloc(2*128*8*8*8),   *s5 = alloc(2*128*8*8*16),  *s6 = alloc(2*128*4*4*16),
      *sf1 = alloc(2*128*32), *sf2 = alloc(2*128*32);

  pack_w_k<<<(9*4*128 + 255)/256, 256, 0, stream>>>(w2, wp2, 128, 128);
  pack_w_k<<<(9*4*256 + 255)/256, 256, 0, stream>>>(w3, wp3, 128, 256);
  pack_w_k<<<(9*8*256 + 255)/256, 256, 0, stream>>>(w4, wp4, 256, 256);
  pack_w_k<<<(9*8*512 + 255)/256, 256, 0, stream>>>(w5, wp5, 256, 512);
  pack_w_k<<<(9*16*512 + 255)/256, 256, 0, stream>>>(w6, wp6, 512, 512);
  pack_fc1_k<<<(1024*256)/256, 256, 0, stream>>>(fw1, fw1p);
  pack_fc_k<<<(1024*32 + 255)/256, 256, 0, stream>>>(fw2, fw2p, 1024, 1024);
  pack_fc_k<<<(10*32 + 255)/256, 256, 0, stream>>>(fw3, fw3p, 1024, 10);

  conv1_k<<<(128*32*32*2)/4, 256, 0, stream>>>(x, w1, c1b, g1, bt1, s1);
  bconv_k<4, 128, 32, 32, 1><<<(128*16*16*2)/4, 256, 0, stream>>>(s1, wp2, g2, bt2, s2);
  bconv_k<4, 256, 16, 16, 0><<<(128*16*16*4)/4, 256, 0, stream>>>(s2, wp3, g3, bt3, s3);
  bconv_k<8, 256, 16, 16, 1><<<(128*8*8*4)/4,   256, 0, stream>>>(s3, wp4, g4, bt4, s4);
  bconv_k<8, 512, 8, 8, 0><<<(128*8*8*8)/4,     256, 0, stream>>>(s4, wp5, g5, bt5, s5);
  bconv_k<16, 512, 8, 8, 1><<<(128*4*4*8)/4,    256, 0, stream>>>(s5, wp6, g6, bt6, s6);
  fcb_k<256><<<(128*16)/4, 256, 0, stream>>>(s6,  fw1p, fb1, gf1, btf1, sf1);
  fcb_k<32><<<(128*16)/4,  256, 0, stream>>>(sf1, fw2p, fb2, gf2, btf2, sf2);
  fc3_k<<<128, 64, 0, stream>>>(sf2, fw3p, fb3, gf3, btf3, (float*)d_out);
}

// Round 7
// 1179.639 us; speedup vs baseline: 1.3154x; 1.3154x over previous
//
#include <hip/hip_runtime.h>
#include <hip/hip_bf16.h>

using u32 = unsigned int;
using u64 = unsigned long long;

// f32 threshold exactly as the reference elementwise ops: rs = 1/sqrt(1+eps),
// s = g*rs, t = z*s + b, all separately rounded f32 (no FMA).
__device__ __forceinline__ float bn_t32(float z, float g, float b){
  const float rs = __fdiv_rn(1.0f, __fsqrt_rn((float)(1.0 + 1e-5)));
  float s = __fmul_rn(g, rs);
  return __fadd_rn(__fmul_rn(z, s), b);
}

// ---------------------------------------------------------------------------
// Ternary weight pack: conv weights [COUT][CIN][3][3] -> wp[tap][ciw][COUT][2]
// plane 0 (A) bit j = (w != 0), plane 1 (S) bit j = (w > 0)
// ---------------------------------------------------------------------------
__global__ void pack_w_k(const float* __restrict__ w, u32* __restrict__ wp,
                         int CIN, int COUT){
  int CW = CIN >> 5;
  int total = COUT * 9 * CW;
  int idx = blockIdx.x * 256 + threadIdx.x;
  if (idx >= total) return;
  int co = idx % COUT; int t = idx / COUT;
  int ciw = t % CW; int tap = t / CW;
  u32 a = 0, s = 0;
  for (int j = 0; j < 32; j++){
    float v = w[(co*CIN + (ciw*32 + j))*9 + tap];
    a |= (v != 0.f ? 1u : 0u) << j;
    s |= (v >  0.f ? 1u : 0u) << j;
  }
  wp[idx*2]   = a;
  wp[idx*2+1] = s;
}

// w1 ternary sign pack: [128][3][9] -> wp1[co] = uint2{A,S}, bit idx tap*3+ci
__global__ void pack_w1_k(const float* __restrict__ w1, u32* __restrict__ wp1){
  int co = blockIdx.x * 64 + threadIdx.x;
  if (co >= 128) return;
  u32 a = 0, s = 0;
  for (int tap = 0; tap < 9; tap++){
    for (int ci = 0; ci < 3; ci++){
      float v = w1[(co*3 + ci)*9 + tap];
      int bit = tap*3 + ci;
      a |= (v != 0.f ? 1u : 0u) << bit;
      s |= (v >  0.f ? 1u : 0u) << bit;
    }
  }
  wp1[co*2]   = a;
  wp1[co*2+1] = s;
}

// FC weight pack: w [COUT][K] -> wp[kw][COUT][2]
__global__ void pack_fc_k(const float* __restrict__ w, u32* __restrict__ wp,
                          int K, int COUT){
  int KW = K >> 5;
  int total = COUT * KW;
  int idx = blockIdx.x * 256 + threadIdx.x;
  if (idx >= total) return;
  int co = idx % COUT; int kw = idx / COUT;
  u32 a = 0, s = 0;
  for (int j = 0; j < 32; j++){
    float v = w[co*K + kw*32 + j];
    a |= (v != 0.f ? 1u : 0u) << j;
    s |= (v >  0.f ? 1u : 0u) << j;
  }
  wp[(kw*COUT + co)*2]   = a;
  wp[(kw*COUT + co)*2+1] = s;
}

// fc1 weight pack, K permuted to our [y][x][cw] layout: k = c*16 + y*4 + x
__global__ void pack_fc1_k(const float* __restrict__ w, u32* __restrict__ wp){
  int idx = blockIdx.x * 256 + threadIdx.x;   // 1024*256
  int co = idx % 1024; int kw = idx / 1024;
  int px = kw >> 4, cw = kw & 15;
  u32 a = 0, s = 0;
  for (int j = 0; j < 32; j++){
    float v = w[co*8192 + (cw*32 + j)*16 + px];
    a |= (v != 0.f ? 1u : 0u) << j;
    s |= (v >  0.f ? 1u : 0u) << j;
  }
  wp[(kw*1024 + co)*2]   = a;
  wp[(kw*1024 + co)*2+1] = s;
}

// ---------------------------------------------------------------------------
// conv1 v2: packed w1 signs (one uint2 per lane, coalesced) replace the 27
// per-lane strided gathers. Arithmetic order identical to round 6:
// tap-major, ci-inner, separate f32 roundings -> bit-identical s1.
// ---------------------------------------------------------------------------
__global__ __launch_bounds__(256) void conv1_k(
    const float* __restrict__ x, const u32* __restrict__ wp1,
    const float* __restrict__ c1b,
    const float* __restrict__ g1, const float* __restrict__ bt1,
    u32* __restrict__ s1p){
  int tid = threadIdx.x; int lane = tid & 63; int wv = tid >> 6;
  int wid = blockIdx.x*4 + wv;                 // 128*32*32*2 waves
  int cg = wid & 1; int p = wid >> 1;
  int xx = p & 31; p >>= 5; int yy = p & 31; int n = p >> 5;
  int co = cg*64 + lane;
  u32 wA = wp1[co*2], wS = wp1[co*2+1];
  const float* xb = x + (size_t)n*3*1024;
  float acc = 0.f;
  #pragma unroll
  for (int tap = 0; tap < 9; tap++){
    int dy = tap/3 - 1, dx = tap%3 - 1;
    int iy = yy + dy, ix = xx + dx;
    if (iy < 0 || iy > 31 || ix < 0 || ix > 31) continue;
    float pt = 0.f;
    #pragma unroll
    for (int ci = 0; ci < 3; ci++){
      int bit = tap*3 + ci;
      float xv = xb[(ci*32 + iy)*32 + ix];
      float sg = ((wA >> bit) & 1u) ? (((wS >> bit) & 1u) ? 1.f : -1.f) : 0.f;
      pt = __fadd_rn(pt, __fmul_rn(sg, xv));
    }
    acc = __fadd_rn(acc, pt);
  }
  float v = __fadd_rn(acc, c1b[co]);
  float t = bn_t32(v, g1[co], bt1[co]);
  u64 mP = __ballot(t > 0.f);
  u64 mN = __ballot(t < 0.f);
  if (lane == 0){
    int o = (((n*32 + yy)*32 + xx)*4 + cg*2)*2;
    s1p[o]   = (u32)(mP | mN);       // A plane, low word
    s1p[o+1] = (u32)mP;              // S plane, low word
    s1p[o+2] = (u32)((mP | mN) >> 32);
    s1p[o+3] = (u32)(mP >> 32);
  }
}

// ---------------------------------------------------------------------------
// Ternary bconv (+optional pool) + f32 bn + ternary double-ballot.
// A: [N][H][W][CW][2]; Wp: [9][CW][COUT][2]; Op: [N][HO][WO][COUT/32][2]
// ---------------------------------------------------------------------------
template<int CW, int COUT, int H, int W, int POOL>
__global__ __launch_bounds__(256) void bconv_k(
    const u32* __restrict__ A, const u32* __restrict__ Wp,
    const float* __restrict__ g, const float* __restrict__ bt,
    u32* __restrict__ Op){
  constexpr int CG = COUT / 64;
  constexpr int HO = POOL ? H/2 : H;
  constexpr int WO = POOL ? W/2 : W;
  constexpr int PX = POOL ? 2 : 1;
  int tid = threadIdx.x; int lane = tid & 63; int wv = tid >> 6;
  int wid = blockIdx.x*4 + wv;
  int cg = wid % CG; int r = wid / CG;
  int ox = r % WO; r /= WO; int oy = r % HO; int n = r / HO;
  int co = cg*64 + lane;

  int zacc[PX*PX];
  #pragma unroll
  for (int i = 0; i < PX*PX; i++) zacc[i] = 0;
  int iy0 = POOL ? oy*2 : oy;
  int ix0 = POOL ? ox*2 : ox;

  #pragma unroll
  for (int tap = 0; tap < 9; tap++){
    int dy = tap/3 - 1, dx = tap%3 - 1;
    u32 wA[CW], wS[CW];
    #pragma unroll
    for (int cw = 0; cw < CW; cw++){
      uint2 wpair = reinterpret_cast<const uint2*>(Wp)[(tap*CW + cw)*COUT + co];
      wA[cw] = wpair.x; wS[cw] = wpair.y;
    }
    #pragma unroll
    for (int py = 0; py < PX; py++){
      int y = iy0 + py + dy; if (y < 0 || y >= H) continue;
      #pragma unroll
      for (int px = 0; px < PX; px++){
        int x = ix0 + px + dx; if (x < 0 || x >= W) continue;
        const uint2* ap = reinterpret_cast<const uint2*>(
            &A[((((size_t)n*H + y)*W + x)*CW)*2]);
        int zz = 0;
        #pragma unroll
        for (int cw = 0; cw < CW; cw++){
          uint2 av = ap[cw];
          u32 v = av.x & wA[cw];
          u32 d = v & (av.y ^ wS[cw]);
          zz += __popc(v) - 2*__popc(d);
        }
        zacc[py*PX+px] += zz;
      }
    }
  }
  int zbest = zacc[0];
  #pragma unroll
  for (int i = 1; i < PX*PX; i++) zbest = max(zbest, zacc[i]);
  float t = bn_t32((float)zbest, g[co], bt[co]);
  u64 mP = __ballot(t > 0.f);
  u64 mN = __ballot(t < 0.f);
  if (lane == 0){
    int o = ((((n*HO) + oy)*WO + ox)*(COUT/32) + cg*2)*2;
    Op[o]   = (u32)(mP | mN);
    Op[o+1] = (u32)mP;
    Op[o+2] = (u32)((mP | mN) >> 32);
    Op[o+3] = (u32)(mP >> 32);
  }
}

// ---------------------------------------------------------------------------
// Ternary FC + f32 bn + ternary ballot. A:[128][KW][2], Wp:[KW][1024][2],
// Op:[128][32][2].
// ---------------------------------------------------------------------------
template<int KW>
__global__ __launch_bounds__(256) void fcb_k(
    const u32* __restrict__ A, const u32* __restrict__ Wp,
    const float* __restrict__ fb,
    const float* __restrict__ g, const float* __restrict__ bt,
    u32* __restrict__ Op){
  int tid = threadIdx.x; int lane = tid & 63; int wv = tid >> 6;
  int wid = blockIdx.x*4 + wv;          // 128*16 waves
  int og = wid & 15; int n = wid >> 4;
  int o = og*64 + lane;
  const uint2* a = reinterpret_cast<const uint2*>(&A[(size_t)n*KW*2]);
  int z = 0;
  #pragma unroll 8
  for (int kw = 0; kw < KW; kw++){
    uint2 av = a[kw];
    uint2 wv_ = reinterpret_cast<const uint2*>(Wp)[kw*1024 + o];
    u32 v = av.x & wv_.x;
    u32 d = v & (av.y ^ wv_.y);
    z += __popc(v) - 2*__popc(d);
  }
  float vv = __fadd_rn((float)z, fb[o]);
  float t = bn_t32(vv, g[o], bt[o]);
  u64 mP = __ballot(t > 0.f);
  u64 mN = __ballot(t < 0.f);
  if (lane == 0){
    int ob = (n*32 + og*2)*2;
    Op[ob]   = (u32)(mP | mN);
    Op[ob+1] = (u32)mP;
    Op[ob+2] = (u32)((mP | mN) >> 32);
    Op[ob+3] = (u32)(mP >> 32);
  }
}

// fc3 (10 outputs) + bn + log_softmax (f64 smooth tail) -> f32 out [128][10]
__global__ void fc3_k(const u32* __restrict__ A, const u32* __restrict__ Wp,
                      const float* __restrict__ fb,
                      const float* __restrict__ g,
                      const float* __restrict__ bt,
                      float* __restrict__ out){
  int n = blockIdx.x; int lane = threadIdx.x;   // blockDim = 64
  __shared__ double ls[10];
  double t = 0.0;
  if (lane < 10){
    const uint2* a = reinterpret_cast<const uint2*>(&A[(size_t)n*32*2]);
    int z = 0;
    for (int kw = 0; kw < 32; kw++){
      uint2 av = a[kw];
      uint2 wv_ = reinterpret_cast<const uint2*>(Wp)[kw*10 + lane];
      u32 v = av.x & wv_.x;
      u32 d = v & (av.y ^ wv_.y);
      z += __popc(v) - 2*__popc(d);
    }
    float vv = __fadd_rn((float)z, fb[lane]);
    float tf = bn_t32(vv, g[lane], bt[lane]);
    t = (double)tf;
    ls[lane] = t;
  }
  __syncthreads();
  if (lane < 10){
    double m = -1e300;
    for (int j = 0; j < 10; j++) m = fmax(m, ls[j]);
    double sum = 0.0;
    for (int j = 0; j < 10; j++) sum += exp(ls[j] - m);
    double r = t - m - log(sum);
    out[n*10 + lane] = (float)r;
  }
}

extern "C" void kernel_launch(void* const* d_in, const int* in_sizes, int n_in,
                              void* d_out, int out_size, void* d_ws, size_t ws_size,
                              hipStream_t stream){
  auto f = [&](int i){ return (const float*)d_in[i]; };
  const float *x  = f(0),  *w1 = f(1),  *c1b = f(2),
    *w2 = f(3),  *w3 = f(4),  *w4 = f(5),  *w5 = f(6),  *w6 = f(7),
    *fw1 = f(8), *fb1 = f(9), *fw2 = f(10), *fb2 = f(11),
    *fw3 = f(12), *fb3 = f(13),
    *g1 = f(14), *bt1 = f(15), *g2 = f(16), *bt2 = f(17),
    *g3 = f(18), *bt3 = f(19), *g4 = f(20), *bt4 = f(21),
    *g5 = f(22), *bt5 = f(23), *g6 = f(24), *bt6 = f(25),
    *gf1 = f(26), *btf1 = f(27), *gf2 = f(28), *btf2 = f(29),
    *gf3 = f(30), *btf3 = f(31);

  u32* W = (u32*)d_ws;
  size_t off = 0;
  auto alloc = [&](size_t words){ u32* p = W + off; off += (words + 63) & ~(size_t)63; return p; };
  // all sizes doubled for the two planes
  u32 *wp1 = alloc(2*128),
      *wp2 = alloc(2*9*4*128),  *wp3 = alloc(2*9*4*256), *wp4 = alloc(2*9*8*256),
      *wp5 = alloc(2*9*8*512),  *wp6 = alloc(2*9*16*512),
      *fw1p = alloc(2*256*1024), *fw2p = alloc(2*32*1024), *fw3p = alloc(2*32*10),
      *s1 = alloc(2*128*32*32*4), *s2 = alloc(2*128*16*16*4), *s3 = alloc(2*128*16*16*8),
      *s4 = alloc(2*128*8*8*8),   *s5 = alloc(2*128*8*8*16),  *s6 = alloc(2*128*4*4*16),
      *sf1 = alloc(2*128*32), *sf2 = alloc(2*128*32);

  pack_w1_k<<<2, 64, 0, stream>>>(w1, wp1);
  pack_w_k<<<(9*4*128 + 255)/256, 256, 0, stream>>>(w2, wp2, 128, 128);
  pack_w_k<<<(9*4*256 + 255)/256, 256, 0, stream>>>(w3, wp3, 128, 256);
  pack_w_k<<<(9*8*256 + 255)/256, 256, 0, stream>>>(w4, wp4, 256, 256);
  pack_w_k<<<(9*8*512 + 255)/256, 256, 0, stream>>>(w5, wp5, 256, 512);
  pack_w_k<<<(9*16*512 + 255)/256, 256, 0, stream>>>(w6, wp6, 512, 512);
  pack_fc1_k<<<(1024*256)/256, 256, 0, stream>>>(fw1, fw1p);
  pack_fc_k<<<(1024*32 + 255)/256, 256, 0, stream>>>(fw2, fw2p, 1024, 1024);
  pack_fc_k<<<(10*32 + 255)/256, 256, 0, stream>>>(fw3, fw3p, 1024, 10);

  conv1_k<<<(128*32*32*2)/4, 256, 0, stream>>>(x, wp1, c1b, g1, bt1, s1);
  bconv_k<4, 128, 32, 32, 1><<<(128*16*16*2)/4, 256, 0, stream>>>(s1, wp2, g2, bt2, s2);
  bconv_k<4, 256, 16, 16, 0><<<(128*16*16*4)/4, 256, 0, stream>>>(s2, wp3, g3, bt3, s3);
  bconv_k<8, 256, 16, 16, 1><<<(128*8*8*4)/4,   256, 0, stream>>>(s3, wp4, g4, bt4, s4);
  bconv_k<8, 512, 8, 8, 0><<<(128*8*8*8)/4,     256, 0, stream>>>(s4, wp5, g5, bt5, s5);
  bconv_k<16, 512, 8, 8, 1><<<(128*4*4*8)/4,    256, 0, stream>>>(s5, wp6, g6, bt6, s6);
  fcb_k<256><<<(128*16)/4, 256, 0, stream>>>(s6,  fw1p, fb1, gf1, btf1, sf1);
  fcb_k<32><<<(128*16)/4,  256, 0, stream>>>(sf1, fw2p, fb2, gf2, btf2, sf2);
  fc3_k<<<128, 64, 0, stream>>>(sf2, fw3p, fb3, gf3, btf3, (float*)d_out);
}

// Round 8
// 798.488 us; speedup vs baseline: 1.9433x; 1.4773x over previous
//
#include <hip/hip_runtime.h>
#include <hip/hip_bf16.h>

using u32 = unsigned int;
using u64 = unsigned long long;

// f32 threshold exactly as the reference elementwise ops: rs = 1/sqrt(1+eps),
// s = g*rs, t = z*s + b, all separately rounded f32 (no FMA).
__device__ __forceinline__ float bn_t32(float z, float g, float b){
  const float rs = __fdiv_rn(1.0f, __fsqrt_rn((float)(1.0 + 1e-5)));
  float s = __fmul_rn(g, rs);
  return __fadd_rn(__fmul_rn(z, s), b);
}

// ---------------------------------------------------------------------------
// conv weight pack v2 (two-phase LDS, coalesced reads). One block per co.
// wp[tap][ciw][COUT][2]: A plane bit j = (w!=0), S plane bit j = (w>0),
// source w[(co*CIN + ciw*32+j)*9 + tap].
// ---------------------------------------------------------------------------
__global__ __launch_bounds__(256) void pack_w2_k(const float* __restrict__ w,
    u32* __restrict__ wp, int CIN, int COUT){
  int co = blockIdx.x;
  __shared__ unsigned char sb[4608];          // max CIN=512: 512*9
  int nf = CIN*9;
  const float* wb = w + (size_t)co*nf;
  for (int i = threadIdx.x; i < nf; i += 256){
    float v = wb[i];
    sb[i] = (unsigned char)(((v != 0.f) ? 2u : 0u) | ((v > 0.f) ? 1u : 0u));
  }
  __syncthreads();
  int CW = CIN >> 5;
  for (int wi = threadIdx.x; wi < 9*CW; wi += 256){
    int tap = wi / CW, ciw = wi % CW;
    u32 a = 0, s = 0;
    for (int j = 0; j < 32; j++){
      unsigned char bch = sb[(ciw*32 + j)*9 + tap];
      a |= (u32)(bch >> 1) << j;
      s |= (u32)(bch & 1u) << j;
    }
    size_t o = ((size_t)(tap*CW + ciw)*COUT + co)*2;
    wp[o] = a; wp[o+1] = s;
  }
}

// w1 ternary sign pack: [128][3][9] -> wp1[co] = {A,S}, bit idx tap*3+ci
__global__ void pack_w1_k(const float* __restrict__ w1, u32* __restrict__ wp1){
  int co = blockIdx.x * 64 + threadIdx.x;
  if (co >= 128) return;
  u32 a = 0, s = 0;
  for (int tap = 0; tap < 9; tap++){
    for (int ci = 0; ci < 3; ci++){
      float v = w1[(co*3 + ci)*9 + tap];
      int bit = tap*3 + ci;
      a |= (v != 0.f ? 1u : 0u) << bit;
      s |= (v >  0.f ? 1u : 0u) << bit;
    }
  }
  wp1[co*2]   = a;
  wp1[co*2+1] = s;
}

// FC weight pack v2: w [COUT][K] -> wp[kw][COUT][2]. One block per co.
__global__ __launch_bounds__(256) void pack_fc2_k(const float* __restrict__ w,
    u32* __restrict__ wp, int K, int COUT){
  int co = blockIdx.x;
  __shared__ unsigned char sb[8192];
  const float* wb = w + (size_t)co*K;
  for (int i = threadIdx.x; i < K; i += 256){
    float v = wb[i];
    sb[i] = (unsigned char)(((v != 0.f) ? 2u : 0u) | ((v > 0.f) ? 1u : 0u));
  }
  __syncthreads();
  int KW = K >> 5;
  for (int kw = threadIdx.x; kw < KW; kw += 256){
    u32 a = 0, s = 0;
    for (int j = 0; j < 32; j++){
      unsigned char bch = sb[kw*32 + j];
      a |= (u32)(bch >> 1) << j;
      s |= (u32)(bch & 1u) << j;
    }
    size_t o = ((size_t)kw*COUT + co)*2;
    wp[o] = a; wp[o+1] = s;
  }
}

// fc1 pack v2, K permuted to our [y][x][cw] layout: k = c*16 + y*4 + x
__global__ __launch_bounds__(256) void pack_fc1_2k(const float* __restrict__ w,
    u32* __restrict__ wp){
  int co = blockIdx.x;                        // 1024 blocks
  __shared__ unsigned char sb[8192];
  const float* wb = w + (size_t)co*8192;
  for (int i = threadIdx.x; i < 8192; i += 256){
    float v = wb[i];
    sb[i] = (unsigned char)(((v != 0.f) ? 2u : 0u) | ((v > 0.f) ? 1u : 0u));
  }
  __syncthreads();
  int kw = threadIdx.x;                       // 256 words exactly
  int px = kw >> 4, cw = kw & 15;
  u32 a = 0, s = 0;
  for (int j = 0; j < 32; j++){
    unsigned char bch = sb[(cw*32 + j)*16 + px];
    a |= (u32)(bch >> 1) << j;
    s |= (u32)(bch & 1u) << j;
  }
  size_t o = ((size_t)kw*1024 + co)*2;
  wp[o] = a; wp[o+1] = s;
}

// ---------------------------------------------------------------------------
// conv1: packed w1 signs, coalesced; arithmetic order identical to round 6.
// ---------------------------------------------------------------------------
__global__ __launch_bounds__(256) void conv1_k(
    const float* __restrict__ x, const u32* __restrict__ wp1,
    const float* __restrict__ c1b,
    const float* __restrict__ g1, const float* __restrict__ bt1,
    u32* __restrict__ s1p){
  int tid = threadIdx.x; int lane = tid & 63; int wv = tid >> 6;
  int wid = blockIdx.x*4 + wv;                 // 128*32*32*2 waves
  int cg = wid & 1; int p = wid >> 1;
  int xx = p & 31; p >>= 5; int yy = p & 31; int n = p >> 5;
  int co = cg*64 + lane;
  u32 wA = wp1[co*2], wS = wp1[co*2+1];
  const float* xb = x + (size_t)n*3*1024;
  float acc = 0.f;
  #pragma unroll
  for (int tap = 0; tap < 9; tap++){
    int dy = tap/3 - 1, dx = tap%3 - 1;
    int iy = yy + dy, ix = xx + dx;
    if (iy < 0 || iy > 31 || ix < 0 || ix > 31) continue;
    float pt = 0.f;
    #pragma unroll
    for (int ci = 0; ci < 3; ci++){
      int bit = tap*3 + ci;
      float xv = xb[(ci*32 + iy)*32 + ix];
      float sg = ((wA >> bit) & 1u) ? (((wS >> bit) & 1u) ? 1.f : -1.f) : 0.f;
      pt = __fadd_rn(pt, __fmul_rn(sg, xv));
    }
    acc = __fadd_rn(acc, pt);
  }
  float v = __fadd_rn(acc, c1b[co]);
  float t = bn_t32(v, g1[co], bt1[co]);
  u64 mP = __ballot(t > 0.f);
  u64 mN = __ballot(t < 0.f);
  if (lane == 0){
    int o = (((n*32 + yy)*32 + xx)*4 + cg*2)*2;
    s1p[o]   = (u32)(mP | mN);
    s1p[o+1] = (u32)mP;
    s1p[o+2] = (u32)((mP | mN) >> 32);
    s1p[o+3] = (u32)(mP >> 32);
  }
}

// ---------------------------------------------------------------------------
// Ternary bconv v2: pixel-blocked (PB outputs/wave), uint4 activation loads,
// weights loaded once per tap per wave. Layouts identical to v1.
// A: [N][H][W][CW][2]; Wp: [9][CW][COUT][2]; Op: [N][HO][WO][COUT/32][2]
// ---------------------------------------------------------------------------
template<int CW, int COUT, int H, int W, int POOL>
__global__ __launch_bounds__(256) void bconv_k(
    const u32* __restrict__ A, const u32* __restrict__ Wp,
    const float* __restrict__ g, const float* __restrict__ bt,
    u32* __restrict__ Op){
  constexpr int CG = COUT / 64;
  constexpr int HO = POOL ? H/2 : H;
  constexpr int WO = POOL ? W/2 : W;
  constexpr int PB = POOL ? 4 : 8;        // output pixels per wave
  constexpr int NCH = WO / PB;            // chunks per output row
  constexpr int NPOS = POOL ? 4 : 1;
  constexpr int PY = POOL ? 2 : 1;
  constexpr int PXN = POOL ? 2 : 1;
  int tid = threadIdx.x; int lane = tid & 63; int wv = tid >> 6;
  int wid = blockIdx.x*4 + wv;
  int cg = wid % CG; int r = wid / CG;
  int ch = r % NCH; r /= NCH;
  int oy = r % HO; int n = r / HO;
  int co = cg*64 + lane;
  int ox0 = ch*PB;

  int zac[PB][NPOS];
  #pragma unroll
  for (int p = 0; p < PB; p++)
    #pragma unroll
    for (int q = 0; q < NPOS; q++) zac[p][q] = 0;

  const u32* Abase = A + (size_t)n*H*W*CW*2;

  #pragma unroll
  for (int tap = 0; tap < 9; tap++){
    const int dy = tap/3 - 1, dx = tap%3 - 1;
    u32 wA[CW], wS[CW];
    #pragma unroll
    for (int cw = 0; cw < CW; cw++){
      uint2 wpair = reinterpret_cast<const uint2*>(Wp)[(tap*CW + cw)*COUT + co];
      wA[cw] = wpair.x; wS[cw] = wpair.y;
    }
    #pragma unroll
    for (int py = 0; py < PY; py++){
      int y = (POOL ? oy*2 + py : oy) + dy;
      if (y < 0 || y >= H) continue;
      #pragma unroll
      for (int p = 0; p < PB; p++){
        #pragma unroll
        for (int px = 0; px < PXN; px++){
          int x = (POOL ? (ox0 + p)*2 + px : (ox0 + p)) + dx;
          if (x < 0 || x >= W) continue;
          const uint4* ap = reinterpret_cast<const uint4*>(
              Abase + ((size_t)y*W + x)*CW*2);
          int zz = 0;
          #pragma unroll
          for (int c2 = 0; c2 < CW/2; c2++){
            uint4 av = ap[c2];
            u32 v0 = av.x & wA[2*c2];
            u32 d0 = v0 & (av.y ^ wS[2*c2]);
            u32 v1 = av.z & wA[2*c2+1];
            u32 d1 = v1 & (av.w ^ wS[2*c2+1]);
            zz += __popc(v0) + __popc(v1) - 2*(__popc(d0) + __popc(d1));
          }
          zac[p][py*2 + px] += zz;
        }
      }
    }
  }

  #pragma unroll
  for (int p = 0; p < PB; p++){
    int zbest = zac[p][0];
    #pragma unroll
    for (int q = 1; q < NPOS; q++) zbest = max(zbest, zac[p][q]);
    float t = bn_t32((float)zbest, g[co], bt[co]);
    u64 mP = __ballot(t > 0.f);
    u64 mN = __ballot(t < 0.f);
    if (lane == 0){
      size_t o = ((((size_t)n*HO + oy)*WO + (ox0 + p))*(COUT/32) + cg*2)*2;
      uint4 st = { (u32)(mP | mN), (u32)mP, (u32)((mP | mN) >> 32), (u32)(mP >> 32) };
      *reinterpret_cast<uint4*>(&Op[o]) = st;
    }
  }
}

// ---------------------------------------------------------------------------
// Ternary FC + f32 bn + ternary ballot. A:[128][KW][2], Wp:[KW][1024][2],
// Op:[128][32][2].
// ---------------------------------------------------------------------------
template<int KW>
__global__ __launch_bounds__(256) void fcb_k(
    const u32* __restrict__ A, const u32* __restrict__ Wp,
    const float* __restrict__ fb,
    const float* __restrict__ g, const float* __restrict__ bt,
    u32* __restrict__ Op){
  int tid = threadIdx.x; int lane = tid & 63; int wv = tid >> 6;
  int wid = blockIdx.x*4 + wv;          // 128*16 waves
  int og = wid & 15; int n = wid >> 4;
  int o = og*64 + lane;
  const uint2* a = reinterpret_cast<const uint2*>(&A[(size_t)n*KW*2]);
  int z = 0;
  #pragma unroll 8
  for (int kw = 0; kw < KW; kw++){
    uint2 av = a[kw];
    uint2 wv_ = reinterpret_cast<const uint2*>(Wp)[kw*1024 + o];
    u32 v = av.x & wv_.x;
    u32 d = v & (av.y ^ wv_.y);
    z += __popc(v) - 2*__popc(d);
  }
  float vv = __fadd_rn((float)z, fb[o]);
  float t = bn_t32(vv, g[o], bt[o]);
  u64 mP = __ballot(t > 0.f);
  u64 mN = __ballot(t < 0.f);
  if (lane == 0){
    int ob = (n*32 + og*2)*2;
    Op[ob]   = (u32)(mP | mN);
    Op[ob+1] = (u32)mP;
    Op[ob+2] = (u32)((mP | mN) >> 32);
    Op[ob+3] = (u32)(mP >> 32);
  }
}

// fc3 (10 outputs) + bn + log_softmax (f64 smooth tail) -> f32 out [128][10]
__global__ void fc3_k(const u32* __restrict__ A, const u32* __restrict__ Wp,
                      const float* __restrict__ fb,
                      const float* __restrict__ g,
                      const float* __restrict__ bt,
                      float* __restrict__ out){
  int n = blockIdx.x; int lane = threadIdx.x;   // blockDim = 64
  __shared__ double ls[10];
  double t = 0.0;
  if (lane < 10){
    const uint2* a = reinterpret_cast<const uint2*>(&A[(size_t)n*32*2]);
    int z = 0;
    for (int kw = 0; kw < 32; kw++){
      uint2 av = a[kw];
      uint2 wv_ = reinterpret_cast<const uint2*>(Wp)[kw*10 + lane];
      u32 v = av.x & wv_.x;
      u32 d = v & (av.y ^ wv_.y);
      z += __popc(v) - 2*__popc(d);
    }
    float vv = __fadd_rn((float)z, fb[lane]);
    float tf = bn_t32(vv, g[lane], bt[lane]);
    t = (double)tf;
    ls[lane] = t;
  }
  __syncthreads();
  if (lane < 10){
    double m = -1e300;
    for (int j = 0; j < 10; j++) m = fmax(m, ls[j]);
    double sum = 0.0;
    for (int j = 0; j < 10; j++) sum += exp(ls[j] - m);
    double r = t - m - log(sum);
    out[n*10 + lane] = (float)r;
  }
}

extern "C" void kernel_launch(void* const* d_in, const int* in_sizes, int n_in,
                              void* d_out, int out_size, void* d_ws, size_t ws_size,
                              hipStream_t stream){
  auto f = [&](int i){ return (const float*)d_in[i]; };
  const float *x  = f(0),  *w1 = f(1),  *c1b = f(2),
    *w2 = f(3),  *w3 = f(4),  *w4 = f(5),  *w5 = f(6),  *w6 = f(7),
    *fw1 = f(8), *fb1 = f(9), *fw2 = f(10), *fb2 = f(11),
    *fw3 = f(12), *fb3 = f(13),
    *g1 = f(14), *bt1 = f(15), *g2 = f(16), *bt2 = f(17),
    *g3 = f(18), *bt3 = f(19), *g4 = f(20), *bt4 = f(21),
    *g5 = f(22), *bt5 = f(23), *g6 = f(24), *bt6 = f(25),
    *gf1 = f(26), *btf1 = f(27), *gf2 = f(28), *btf2 = f(29),
    *gf3 = f(30), *btf3 = f(31);

  u32* W = (u32*)d_ws;
  size_t off = 0;
  auto alloc = [&](size_t words){ u32* p = W + off; off += (words + 63) & ~(size_t)63; return p; };
  // all sizes doubled for the two planes
  u32 *wp1 = alloc(2*128),
      *wp2 = alloc(2*9*4*128),  *wp3 = alloc(2*9*4*256), *wp4 = alloc(2*9*8*256),
      *wp5 = alloc(2*9*8*512),  *wp6 = alloc(2*9*16*512),
      *fw1p = alloc(2*256*1024), *fw2p = alloc(2*32*1024), *fw3p = alloc(2*32*10),
      *s1 = alloc(2*128*32*32*4), *s2 = alloc(2*128*16*16*4), *s3 = alloc(2*128*16*16*8),
      *s4 = alloc(2*128*8*8*8),   *s5 = alloc(2*128*8*8*16),  *s6 = alloc(2*128*4*4*16),
      *sf1 = alloc(2*128*32), *sf2 = alloc(2*128*32);

  pack_w1_k<<<2, 64, 0, stream>>>(w1, wp1);
  pack_w2_k<<<128, 256, 0, stream>>>(w2, wp2, 128, 128);
  pack_w2_k<<<256, 256, 0, stream>>>(w3, wp3, 128, 256);
  pack_w2_k<<<256, 256, 0, stream>>>(w4, wp4, 256, 256);
  pack_w2_k<<<512, 256, 0, stream>>>(w5, wp5, 256, 512);
  pack_w2_k<<<512, 256, 0, stream>>>(w6, wp6, 512, 512);
  pack_fc1_2k<<<1024, 256, 0, stream>>>(fw1, fw1p);
  pack_fc2_k<<<1024, 256, 0, stream>>>(fw2, fw2p, 1024, 1024);
  pack_fc2_k<<<10, 256, 0, stream>>>(fw3, fw3p, 1024, 10);

  conv1_k<<<(128*32*32*2)/4, 256, 0, stream>>>(x, wp1, c1b, g1, bt1, s1);
  // waves = N*HO*NCH*CG; blocks = waves/4
  bconv_k<4, 128, 32, 32, 1><<<(128*16*4*2)/4, 256, 0, stream>>>(s1, wp2, g2, bt2, s2);
  bconv_k<4, 256, 16, 16, 0><<<(128*16*2*4)/4, 256, 0, stream>>>(s2, wp3, g3, bt3, s3);
  bconv_k<8, 256, 16, 16, 1><<<(128*8*2*4)/4,  256, 0, stream>>>(s3, wp4, g4, bt4, s4);
  bconv_k<8, 512, 8, 8, 0><<<(128*8*1*8)/4,    256, 0, stream>>>(s4, wp5, g5, bt5, s5);
  bconv_k<16, 512, 8, 8, 1><<<(128*4*1*8)/4,   256, 0, stream>>>(s5, wp6, g6, bt6, s6);
  fcb_k<256><<<(128*16)/4, 256, 0, stream>>>(s6,  fw1p, fb1, gf1, btf1, sf1);
  fcb_k<32><<<(128*16)/4,  256, 0, stream>>>(sf1, fw2p, fb2, gf2, btf2, sf2);
  fc3_k<<<128, 64, 0, stream>>>(sf2, fw3p, fb3, gf3, btf3, (float*)d_out);
}

// Round 9
// 412.503 us; speedup vs baseline: 3.7617x; 1.9357x over previous
//
#include <hip/hip_runtime.h>
#include <hip/hip_bf16.h>

using u32 = unsigned int;
using u64 = unsigned long long;
using s8  = signed char;
typedef int i32x4  __attribute__((ext_vector_type(4)));
typedef int i32x16 __attribute__((ext_vector_type(16)));

// f32 threshold exactly as the reference elementwise ops (no FMA, separate
// roundings). Verified bit-exact vs np reference in rounds 6-8.
__device__ __forceinline__ float bn_t32(float z, float g, float b){
  const float rs = __fdiv_rn(1.0f, __fsqrt_rn((float)(1.0 + 1e-5)));
  float s = __fmul_rn(g, rs);
  return __fadd_rn(__fmul_rn(z, s), b);
}
__device__ __forceinline__ s8 tsign(float t){
  return (t > 0.f) ? (s8)1 : ((t < 0.f) ? (s8)-1 : (s8)0);
}

// ---------------------------------------------------------------------------
// Conv-weight MFMA-fragment pack. One block per co. B-frag layout:
// wf[(((tap*KK + kk)*CG + cg)*64 + l)*16 + e], where for weight element
// (co, k, tap): cg=co>>5, l=(co&31)+((k>>4)&1)*32, kk=k>>5, e=k&15.
// Same (position->k) map as the A-side NHWC storage -> Σ_k invariant.
// ---------------------------------------------------------------------------
__global__ __launch_bounds__(256) void pack_wfrag_k(const float* __restrict__ w,
    s8* __restrict__ wf, int CIN, int COUT){
  int co = blockIdx.x;
  __shared__ s8 sb[4608];                    // max CIN=512: 512*9
  int nf = CIN*9;
  const float* wb = w + (size_t)co*nf;
  for (int i = threadIdx.x; i < nf; i += 256){
    float v = wb[i];
    sb[i] = (v > 0.f) ? (s8)1 : ((v < 0.f) ? (s8)-1 : (s8)0);
  }
  __syncthreads();
  int KK = CIN >> 5, CG = COUT >> 5;
  int cg = co >> 5, llo = co & 31;
  for (int i = threadIdx.x; i < nf; i += 256){
    int tap = i / CIN, k = i - tap*CIN;
    s8 v = sb[k*9 + tap];
    size_t dst = ((((size_t)tap*KK + (k>>5))*CG + cg)*64
                  + (llo + ((k>>4)&1)*32))*16 + (k&15);
    wf[dst] = v;
  }
}

// w1 ternary sign pack: [128][3][9] -> wp1[co] = {A,S}, bit idx tap*3+ci
__global__ void pack_w1_k(const float* __restrict__ w1, u32* __restrict__ wp1){
  int co = blockIdx.x * 64 + threadIdx.x;
  if (co >= 128) return;
  u32 a = 0, s = 0;
  for (int tap = 0; tap < 9; tap++){
    for (int ci = 0; ci < 3; ci++){
      float v = w1[(co*3 + ci)*9 + tap];
      int bit = tap*3 + ci;
      a |= (v != 0.f ? 1u : 0u) << bit;
      s |= (v >  0.f ? 1u : 0u) << bit;
    }
  }
  wp1[co*2]   = a;
  wp1[co*2+1] = s;
}

// FC weight pack (ternary bitplanes): w [COUT][K] -> wp[kw][COUT][2]
__global__ __launch_bounds__(256) void pack_fc2_k(const float* __restrict__ w,
    u32* __restrict__ wp, int K, int COUT){
  int co = blockIdx.x;
  __shared__ unsigned char sb[8192];
  const float* wb = w + (size_t)co*K;
  for (int i = threadIdx.x; i < K; i += 256){
    float v = wb[i];
    sb[i] = (unsigned char)(((v != 0.f) ? 2u : 0u) | ((v > 0.f) ? 1u : 0u));
  }
  __syncthreads();
  int KW = K >> 5;
  for (int kw = threadIdx.x; kw < KW; kw += 256){
    u32 a = 0, s = 0;
    for (int j = 0; j < 32; j++){
      unsigned char bch = sb[kw*32 + j];
      a |= (u32)(bch >> 1) << j;
      s |= (u32)(bch & 1u) << j;
    }
    size_t o = ((size_t)kw*COUT + co)*2;
    wp[o] = a; wp[o+1] = s;
  }
}

// fc1 pack, K permuted to [px][cw] word order: k = c*16 + px, kw = px*16+cw
__global__ __launch_bounds__(256) void pack_fc1_2k(const float* __restrict__ w,
    u32* __restrict__ wp){
  int co = blockIdx.x;                        // 1024 blocks
  __shared__ unsigned char sb[8192];
  const float* wb = w + (size_t)co*8192;
  for (int i = threadIdx.x; i < 8192; i += 256){
    float v = wb[i];
    sb[i] = (unsigned char)(((v != 0.f) ? 2u : 0u) | ((v > 0.f) ? 1u : 0u));
  }
  __syncthreads();
  int kw = threadIdx.x;                       // 256 words exactly
  int px = kw >> 4, cw = kw & 15;
  u32 a = 0, s = 0;
  for (int j = 0; j < 32; j++){
    unsigned char bch = sb[(cw*32 + j)*16 + px];
    a |= (u32)(bch >> 1) << j;
    s |= (u32)(bch & 1u) << j;
  }
  size_t o = ((size_t)kw*1024 + co)*2;
  wp[o] = a; wp[o+1] = s;
}

// ---------------------------------------------------------------------------
// conv1: numerics identical to rounds 6-8; output now int8 NHWC
// s1[n][y][x][co] in {-1,0,+1}.
// ---------------------------------------------------------------------------
__global__ __launch_bounds__(256) void conv1_k(
    const float* __restrict__ x, const u32* __restrict__ wp1,
    const float* __restrict__ c1b,
    const float* __restrict__ g1, const float* __restrict__ bt1,
    s8* __restrict__ s1){
  int tid = threadIdx.x; int lane = tid & 63; int wv = tid >> 6;
  int wid = blockIdx.x*4 + wv;                 // 128*32*32*2 waves
  int cg = wid & 1; int p = wid >> 1;
  int xx = p & 31; p >>= 5; int yy = p & 31; int n = p >> 5;
  int co = cg*64 + lane;
  u32 wA = wp1[co*2], wS = wp1[co*2+1];
  const float* xb = x + (size_t)n*3*1024;
  float acc = 0.f;
  #pragma unroll
  for (int tap = 0; tap < 9; tap++){
    int dy = tap/3 - 1, dx = tap%3 - 1;
    int iy = yy + dy, ix = xx + dx;
    if (iy < 0 || iy > 31 || ix < 0 || ix > 31) continue;
    float pt = 0.f;
    #pragma unroll
    for (int ci = 0; ci < 3; ci++){
      int bit = tap*3 + ci;
      float xv = xb[(ci*32 + iy)*32 + ix];
      float sg = ((wA >> bit) & 1u) ? (((wS >> bit) & 1u) ? 1.f : -1.f) : 0.f;
      pt = __fadd_rn(pt, __fmul_rn(sg, xv));
    }
    acc = __fadd_rn(acc, pt);
  }
  float v = __fadd_rn(acc, c1b[co]);
  float t = bn_t32(v, g1[co], bt1[co]);
  s1[(((size_t)(n*32 + yy)*32 + xx))*128 + co] = tsign(t);
}

// ---------------------------------------------------------------------------
// MFMA ternary bconv (+ in-register 2x2 pool) + f32 bn + ternary int8 out.
// A: int8 NHWC [N][H][W][CIN]; WF: fragment-packed (see pack_wfrag_k);
// O: int8 NHWC [N][HO][WO][COUT].
// Wave = 32-pixel tile (YT x XT) x 64 couts (2 cout-groups sharing A).
// OOB taps feed zero A-fragments == sign(0)=0 zero padding, exactly.
// Pool partners live in-lane: regs {r,r^1,r^RY,r^RY+1}.
// ---------------------------------------------------------------------------
template<int CIN, int COUT, int H, int W, int POOL>
__global__ __launch_bounds__(256) void bconv_m(
    const s8* __restrict__ A, const s8* __restrict__ WF,
    const float* __restrict__ g, const float* __restrict__ bt,
    s8* __restrict__ O){
  constexpr int KK = CIN/32, CG = COUT/32, CGB = 2;
  constexpr int XT = (W >= 16) ? 16 : 8;
  constexpr int YT = 32 / XT;
  constexpr int TPR = W / XT;
  constexpr int TROWS = H / YT;
  constexpr int HO = POOL ? H/2 : H, WO = POOL ? W/2 : W;
  int tid = threadIdx.x, lane = tid & 63, wv = tid >> 6;
  int wid = blockIdx.x*4 + wv;
  int cb = wid % (CG/CGB); int mt = wid / (CG/CGB);
  int tx = mt % TPR; int r0 = mt / TPR;
  int ty = r0 % TROWS; int n = r0 / TROWS;
  int y0 = ty*YT, x0 = tx*XT;
  int p = lane & 31;
  int py = p / XT, px = p % XT;
  int y = y0 + py, x = x0 + px;
  int kh = lane >> 5;
  const s8* An = A + (size_t)n*H*W*CIN;

  i32x16 acc0 = {0,0,0,0,0,0,0,0,0,0,0,0,0,0,0,0};
  i32x16 acc1 = {0,0,0,0,0,0,0,0,0,0,0,0,0,0,0,0};

  #pragma unroll
  for (int tap = 0; tap < 9; tap++){
    int dy = tap/3 - 1, dx = tap%3 - 1;
    int sy = y + dy, sx = x + dx;
    bool ok = ((unsigned)sy < (unsigned)H) && ((unsigned)sx < (unsigned)W);
    const s8* ap = An + ((size_t)sy*W + sx)*CIN + kh*16;
    const s8* wp = WF + (((size_t)tap*KK)*CG + (size_t)cb*CGB)*1024 + lane*16;
    #pragma unroll
    for (int kk = 0; kk < KK; kk++){
      i32x4 av = {0,0,0,0};
      if (ok) av = *reinterpret_cast<const i32x4*>(ap + kk*32);
      const s8* wk = wp + (size_t)kk*CG*1024;
      i32x4 b0 = *reinterpret_cast<const i32x4*>(wk);
      i32x4 b1 = *reinterpret_cast<const i32x4*>(wk + 1024);
      acc0 = __builtin_amdgcn_mfma_i32_32x32x32_i8(av, b0, acc0, 0, 0, 0);
      acc1 = __builtin_amdgcn_mfma_i32_32x32x32_i8(av, b1, acc1, 0, 0, 0);
    }
  }

  #pragma unroll
  for (int cgb = 0; cgb < CGB; cgb++){
    i32x16 acc = cgb ? acc1 : acc0;
    int co = (cb*CGB + cgb)*32 + (lane & 31);
    float gg = g[co], bb = bt[co];
    if (POOL){
      constexpr int RY = (XT == 16) ? 8 : 4;
      #pragma unroll
      for (int q = 0; q < 4; q++){
        int rr = (q&1)*2 + (q>>1)*((XT == 16) ? 4 : 8);
        int z = max(max(acc[rr], acc[rr+1]), max(acc[rr+RY], acc[rr+RY+1]));
        int pb = (rr&3) + 8*(rr>>2) + 4*kh;
        int yy = y0 + pb/XT, xx2 = x0 + pb%XT;
        int oy = yy >> 1, ox = xx2 >> 1;
        float t = bn_t32((float)z, gg, bb);
        O[(((size_t)n*HO + oy)*WO + ox)*COUT + co] = tsign(t);
      }
    } else {
      #pragma unroll
      for (int rr = 0; rr < 16; rr++){
        int pb = (rr&3) + 8*(rr>>2) + 4*kh;
        int yy = y0 + pb/XT, xx2 = x0 + pb%XT;
        float t = bn_t32((float)acc[rr], gg, bb);
        O[(((size_t)n*H + yy)*W + xx2)*COUT + co] = tsign(t);
      }
    }
  }
}

// s6 int8 NHWC [128][4][4][512] -> ternary bitplanes [n][kw=px*16+cw][2]
__global__ void repack6_k(const s8* __restrict__ s6, u32* __restrict__ Op){
  int idx = blockIdx.x*256 + threadIdx.x;   // 128*256
  if (idx >= 128*256) return;
  int n = idx >> 8, kw = idx & 255;
  int px = kw >> 4, cw = kw & 15;
  const s8* p = s6 + ((size_t)n*16 + px)*512 + cw*32;
  u32 a = 0, s = 0;
  for (int j = 0; j < 32; j++){
    s8 v = p[j];
    a |= (u32)(v != 0) << j;
    s |= (u32)(v > 0) << j;
  }
  Op[((size_t)n*256 + kw)*2]   = a;
  Op[((size_t)n*256 + kw)*2+1] = s;
}

// ---------------------------------------------------------------------------
// Ternary FC + f32 bn + ternary ballot (bitplanes). Unchanged from round 8.
// ---------------------------------------------------------------------------
template<int KW>
__global__ __launch_bounds__(256) void fcb_k(
    const u32* __restrict__ A, const u32* __restrict__ Wp,
    const float* __restrict__ fb,
    const float* __restrict__ g, const float* __restrict__ bt,
    u32* __restrict__ Op){
  int tid = threadIdx.x; int lane = tid & 63; int wv = tid >> 6;
  int wid = blockIdx.x*4 + wv;          // 128*16 waves
  int og = wid & 15; int n = wid >> 4;
  int o = og*64 + lane;
  const uint2* a = reinterpret_cast<const uint2*>(&A[(size_t)n*KW*2]);
  int z = 0;
  #pragma unroll 8
  for (int kw = 0; kw < KW; kw++){
    uint2 av = a[kw];
    uint2 wv_ = reinterpret_cast<const uint2*>(Wp)[kw*1024 + o];
    u32 v = av.x & wv_.x;
    u32 d = v & (av.y ^ wv_.y);
    z += __popc(v) - 2*__popc(d);
  }
  float vv = __fadd_rn((float)z, fb[o]);
  float t = bn_t32(vv, g[o], bt[o]);
  u64 mP = __ballot(t > 0.f);
  u64 mN = __ballot(t < 0.f);
  if (lane == 0){
    int ob = (n*32 + og*2)*2;
    Op[ob]   = (u32)(mP | mN);
    Op[ob+1] = (u32)mP;
    Op[ob+2] = (u32)((mP | mN) >> 32);
    Op[ob+3] = (u32)(mP >> 32);
  }
}

// fc3 (10 outputs) + bn + log_softmax -> f32 out [128][10]
__global__ void fc3_k(const u32* __restrict__ A, const u32* __restrict__ Wp,
                      const float* __restrict__ fb,
                      const float* __restrict__ g,
                      const float* __restrict__ bt,
                      float* __restrict__ out){
  int n = blockIdx.x; int lane = threadIdx.x;   // blockDim = 64
  __shared__ double ls[10];
  double t = 0.0;
  if (lane < 10){
    const uint2* a = reinterpret_cast<const uint2*>(&A[(size_t)n*32*2]);
    int z = 0;
    for (int kw = 0; kw < 32; kw++){
      uint2 av = a[kw];
      uint2 wv_ = reinterpret_cast<const uint2*>(Wp)[kw*10 + lane];
      u32 v = av.x & wv_.x;
      u32 d = v & (av.y ^ wv_.y);
      z += __popc(v) - 2*__popc(d);
    }
    float vv = __fadd_rn((float)z, fb[lane]);
    float tf = bn_t32(vv, g[lane], bt[lane]);
    t = (double)tf;
    ls[lane] = t;
  }
  __syncthreads();
  if (lane < 10){
    double m = -1e300;
    for (int j = 0; j < 10; j++) m = fmax(m, ls[j]);
    double sum = 0.0;
    for (int j = 0; j < 10; j++) sum += exp(ls[j] - m);
    double r = t - m - log(sum);
    out[n*10 + lane] = (float)r;
  }
}

extern "C" void kernel_launch(void* const* d_in, const int* in_sizes, int n_in,
                              void* d_out, int out_size, void* d_ws, size_t ws_size,
                              hipStream_t stream){
  auto f = [&](int i){ return (const float*)d_in[i]; };
  const float *x  = f(0),  *w1 = f(1),  *c1b = f(2),
    *w2 = f(3),  *w3 = f(4),  *w4 = f(5),  *w5 = f(6),  *w6 = f(7),
    *fw1 = f(8), *fb1 = f(9), *fw2 = f(10), *fb2 = f(11),
    *fw3 = f(12), *fb3 = f(13),
    *g1 = f(14), *bt1 = f(15), *g2 = f(16), *bt2 = f(17),
    *g3 = f(18), *bt3 = f(19), *g4 = f(20), *bt4 = f(21),
    *g5 = f(22), *bt5 = f(23), *g6 = f(24), *bt6 = f(25),
    *gf1 = f(26), *btf1 = f(27), *gf2 = f(28), *btf2 = f(29),
    *gf3 = f(30), *btf3 = f(31);

  char* base = (char*)d_ws;
  size_t off = 0;
  auto alloc = [&](size_t bytes){ char* p = base + off; off += (bytes + 255) & ~(size_t)255; return p; };
  // activation pools (int8 NHWC), lifetimes alternate A/B
  s8* poolA = (s8*)alloc(128ull*32*32*128);       // s1 / s3 / s5
  s8* poolB = (s8*)alloc(128ull*16*16*128);       // s2 / s4 / s6
  s8 *s1 = poolA, *s3 = poolA, *s5 = poolA;
  s8 *s2 = poolB, *s4 = poolB, *s6 = poolB;
  // weight fragments
  s8 *wf2 = (s8*)alloc(9ull*128*128), *wf3 = (s8*)alloc(9ull*128*256),
     *wf4 = (s8*)alloc(9ull*256*256), *wf5 = (s8*)alloc(9ull*256*512),
     *wf6 = (s8*)alloc(9ull*512*512);
  // bitplane weights + fc activations
  u32 *wp1  = (u32*)alloc(2*128*4);
  u32 *fw1p = (u32*)alloc(2ull*256*1024*4), *fw2p = (u32*)alloc(2ull*32*1024*4),
      *fw3p = (u32*)alloc(2ull*32*10*4);
  u32 *s6p  = (u32*)alloc(2ull*128*256*4);
  u32 *sf1  = (u32*)alloc(2ull*128*32*4), *sf2 = (u32*)alloc(2ull*128*32*4);

  // weight packing
  pack_w1_k<<<2, 64, 0, stream>>>(w1, wp1);
  pack_wfrag_k<<<128, 256, 0, stream>>>(w2, wf2, 128, 128);
  pack_wfrag_k<<<256, 256, 0, stream>>>(w3, wf3, 128, 256);
  pack_wfrag_k<<<256, 256, 0, stream>>>(w4, wf4, 256, 256);
  pack_wfrag_k<<<512, 256, 0, stream>>>(w5, wf5, 256, 512);
  pack_wfrag_k<<<512, 256, 0, stream>>>(w6, wf6, 512, 512);
  pack_fc1_2k<<<1024, 256, 0, stream>>>(fw1, fw1p);
  pack_fc2_k<<<1024, 256, 0, stream>>>(fw2, fw2p, 1024, 1024);
  pack_fc2_k<<<10, 256, 0, stream>>>(fw3, fw3p, 1024, 10);

  // network
  conv1_k<<<(128*32*32*2)/4, 256, 0, stream>>>(x, wp1, c1b, g1, bt1, s1);
  // waves = 128*(H*W/32)*(CG/2); blocks = waves/4
  bconv_m<128,128,32,32,1><<<2048, 256, 0, stream>>>(s1, wf2, g2, bt2, s2);
  bconv_m<128,256,16,16,0><<<1024, 256, 0, stream>>>(s2, wf3, g3, bt3, s3);
  bconv_m<256,256,16,16,1><<<1024, 256, 0, stream>>>(s3, wf4, g4, bt4, s4);
  bconv_m<256,512, 8, 8,0><<< 512, 256, 0, stream>>>(s4, wf5, g5, bt5, s5);
  bconv_m<512,512, 8, 8,1><<< 512, 256, 0, stream>>>(s5, wf6, g6, bt6, s6);
  repack6_k<<<128, 256, 0, stream>>>(s6, s6p);
  fcb_k<256><<<(128*16)/4, 256, 0, stream>>>(s6p, fw1p, fb1, gf1, btf1, sf1);
  fcb_k<32><<<(128*16)/4,  256, 0, stream>>>(sf1, fw2p, fb2, gf2, btf2, sf2);
  fc3_k<<<128, 64, 0, stream>>>(sf2, fw3p, fb3, gf3, btf3, (float*)d_out);
}

// Round 10
// 369.032 us; speedup vs baseline: 4.2049x; 1.1178x over previous
//
#include <hip/hip_runtime.h>
#include <hip/hip_bf16.h>

using u32 = unsigned int;
using u64 = unsigned long long;
using s8  = signed char;
typedef int i32x4  __attribute__((ext_vector_type(4)));
typedef int i32x16 __attribute__((ext_vector_type(16)));

// f32 threshold exactly as the reference elementwise ops (no FMA, separate
// roundings). Verified bit-exact vs np reference in rounds 6-9.
__device__ __forceinline__ float bn_t32(float z, float g, float b){
  const float rs = __fdiv_rn(1.0f, __fsqrt_rn((float)(1.0 + 1e-5)));
  float s = __fmul_rn(g, rs);
  return __fadd_rn(__fmul_rn(z, s), b);
}
__device__ __forceinline__ s8 tsign(float t){
  return (t > 0.f) ? (s8)1 : ((t < 0.f) ? (s8)-1 : (s8)0);
}

// ---------------------------------------------------------------------------
// Conv-weight MFMA-fragment pack. One block per co. (unchanged from r9)
// ---------------------------------------------------------------------------
__global__ __launch_bounds__(256) void pack_wfrag_k(const float* __restrict__ w,
    s8* __restrict__ wf, int CIN, int COUT){
  int co = blockIdx.x;
  __shared__ s8 sb[4608];
  int nf = CIN*9;
  const float* wb = w + (size_t)co*nf;
  for (int i = threadIdx.x; i < nf; i += 256){
    float v = wb[i];
    sb[i] = (v > 0.f) ? (s8)1 : ((v < 0.f) ? (s8)-1 : (s8)0);
  }
  __syncthreads();
  int KK = CIN >> 5, CG = COUT >> 5;
  int cg = co >> 5, llo = co & 31;
  for (int i = threadIdx.x; i < nf; i += 256){
    int tap = i / CIN, k = i - tap*CIN;
    s8 v = sb[k*9 + tap];
    size_t dst = ((((size_t)tap*KK + (k>>5))*CG + cg)*64
                  + (llo + ((k>>4)&1)*32))*16 + (k&15);
    wf[dst] = v;
  }
}

// ---------------------------------------------------------------------------
// w1 pack v3: bitplanes [co*2..], per-(co,tap) control words [256 + co*9+tap],
// global any-zero flag [1408].
// ctl: bit0 = sign(w0)==sign(w1), bit1 = (w0<0), bit2 = (w2<0)  (ci order)
// ---------------------------------------------------------------------------
__global__ void pack_w1_k(const float* __restrict__ w1, u32* __restrict__ wp1){
  int lane = threadIdx.x;                 // one wave of 64
  bool hz = false;
  for (int h = 0; h < 2; h++){
    int co = h*64 + lane;
    u32 a = 0, s = 0;
    for (int tap = 0; tap < 9; tap++){
      float v0 = w1[(co*3 + 0)*9 + tap];
      float v1 = w1[(co*3 + 1)*9 + tap];
      float v2 = w1[(co*3 + 2)*9 + tap];
      int b0 = tap*3;
      a |= ((v0 != 0.f) ? 1u : 0u) << b0;     s |= ((v0 > 0.f) ? 1u : 0u) << b0;
      a |= ((v1 != 0.f) ? 1u : 0u) << (b0+1); s |= ((v1 > 0.f) ? 1u : 0u) << (b0+1);
      a |= ((v2 != 0.f) ? 1u : 0u) << (b0+2); s |= ((v2 > 0.f) ? 1u : 0u) << (b0+2);
      hz |= (v0 == 0.f) || (v1 == 0.f) || (v2 == 0.f);
      u32 ctl = (((v0 > 0.f) == (v1 > 0.f)) ? 1u : 0u)
              | ((v0 < 0.f) ? 2u : 0u)
              | ((v2 < 0.f) ? 4u : 0u);
      wp1[256 + co*9 + tap] = ctl;
    }
    wp1[co*2]   = a;
    wp1[co*2+1] = s;
  }
  u64 m = __ballot(hz);
  if (lane == 0) wp1[1408] = (m != 0ull) ? 1u : 0u;
}

// FC weight pack (ternary bitplanes): w [COUT][K] -> wp[kw][COUT][2]
__global__ __launch_bounds__(256) void pack_fc2_k(const float* __restrict__ w,
    u32* __restrict__ wp, int K, int COUT){
  int co = blockIdx.x;
  __shared__ unsigned char sb[8192];
  const float* wb = w + (size_t)co*K;
  for (int i = threadIdx.x; i < K; i += 256){
    float v = wb[i];
    sb[i] = (unsigned char)(((v != 0.f) ? 2u : 0u) | ((v > 0.f) ? 1u : 0u));
  }
  __syncthreads();
  int KW = K >> 5;
  for (int kw = threadIdx.x; kw < KW; kw += 256){
    u32 a = 0, s = 0;
    for (int j = 0; j < 32; j++){
      unsigned char bch = sb[kw*32 + j];
      a |= (u32)(bch >> 1) << j;
      s |= (u32)(bch & 1u) << j;
    }
    size_t o = ((size_t)kw*COUT + co)*2;
    wp[o] = a; wp[o+1] = s;
  }
}

// fc1 pack, K permuted to [px][cw] word order: k = c*16 + px, kw = px*16+cw
__global__ __launch_bounds__(256) void pack_fc1_2k(const float* __restrict__ w,
    u32* __restrict__ wp){
  int co = blockIdx.x;                        // 1024 blocks
  __shared__ unsigned char sb[8192];
  const float* wb = w + (size_t)co*8192;
  for (int i = threadIdx.x; i < 8192; i += 256){
    float v = wb[i];
    sb[i] = (unsigned char)(((v != 0.f) ? 2u : 0u) | ((v > 0.f) ? 1u : 0u));
  }
  __syncthreads();
  int kw = threadIdx.x;                       // 256 words exactly
  int px = kw >> 4, cw = kw & 15;
  u32 a = 0, s = 0;
  for (int j = 0; j < 32; j++){
    unsigned char bch = sb[(cw*32 + j)*16 + px];
    a |= (u32)(bch >> 1) << j;
    s |= (u32)(bch & 1u) << j;
  }
  size_t o = ((size_t)kw*1024 + co)*2;
  wp[o] = a; wp[o+1] = s;
}

// ---------------------------------------------------------------------------
// conv1 v3: lanes = 64 pixels (2 rows x 32), couts = wave-uniform loop.
// Per lane: 27-float neighborhood in VGPRs (OOB -> 0.0f, exact pad).
// Per (co,tap): select +/- pair-sum (ctl bit0), xor-negate (bits 1/2) -
// bit-exact vs the verified r6 chain. Fallback to plain muls if any w1 == 0.
// ---------------------------------------------------------------------------
__global__ __launch_bounds__(256) void conv1_k(
    const float* __restrict__ x, const u32* __restrict__ wp1,
    const float* __restrict__ c1b,
    const float* __restrict__ g1, const float* __restrict__ bt1,
    s8* __restrict__ s1){
  int tid = threadIdx.x, lane = tid & 63, wv = tid >> 6;
  int wid = blockIdx.x*4 + wv;          // 4096 waves: [n(128)][chunk(16)][coh(2)]
  int coh = wid & 1;
  int chunk = (wid >> 1) & 15;
  int n = wid >> 5;
  int py = lane >> 5, px = lane & 31;
  int y = chunk*2 + py;
  const float* xb = x + (size_t)n*3*1024;

  float xv[3][9];
  #pragma unroll
  for (int ci = 0; ci < 3; ci++)
    #pragma unroll
    for (int tap = 0; tap < 9; tap++){
      int yy = y + tap/3 - 1, xx = px + tap%3 - 1;
      bool ok = ((unsigned)yy < 32u) && ((unsigned)xx < 32u);
      xv[ci][tap] = ok ? xb[(ci*32 + yy)*32 + xx] : 0.f;
    }
  float pc0[9], pc1[9];
  #pragma unroll
  for (int tap = 0; tap < 9; tap++){
    pc0[tap] = __fadd_rn(xv[0][tap], xv[1][tap]);
    pc1[tap] = __fadd_rn(xv[0][tap], -xv[1][tap]);
  }

  size_t pixbase = (((size_t)n*1024) + y*32 + px)*128 + coh*64;
  bool fallback = (wp1[1408] != 0u);

  if (!fallback){
    for (int co4 = 0; co4 < 64; co4 += 4){
      u32 outw = 0;
      #pragma unroll
      for (int j = 0; j < 4; j++){
        int co = coh*64 + co4 + j;
        float acc = 0.f;
        #pragma unroll
        for (int tap = 0; tap < 9; tap++){
          u32 ctl = wp1[256 + co*9 + tap];     // wave-uniform
          float s01 = (ctl & 1u) ? pc0[tap] : pc1[tap];
          s01 = __uint_as_float(__float_as_uint(s01) ^ ((ctl & 2u) << 30));
          float t2 = __uint_as_float(__float_as_uint(xv[2][tap]) ^ ((ctl & 4u) << 29));
          float pt = __fadd_rn(s01, t2);
          acc = __fadd_rn(acc, pt);
        }
        float v = __fadd_rn(acc, c1b[co]);
        float t = bn_t32(v, g1[co], bt1[co]);
        outw |= ((u32)(unsigned char)tsign(t)) << (8*j);
      }
      *reinterpret_cast<u32*>(&s1[pixbase + co4]) = outw;
    }
  } else {
    for (int co4 = 0; co4 < 64; co4 += 4){
      u32 outw = 0;
      #pragma unroll
      for (int j = 0; j < 4; j++){
        int co = coh*64 + co4 + j;
        u32 wA = wp1[co*2], wS = wp1[co*2+1];
        float acc = 0.f;
        #pragma unroll
        for (int tap = 0; tap < 9; tap++){
          float pt = 0.f;
          #pragma unroll
          for (int ci = 0; ci < 3; ci++){
            int bit = tap*3 + ci;
            float sg = ((wA >> bit) & 1u) ? (((wS >> bit) & 1u) ? 1.f : -1.f) : 0.f;
            pt = __fadd_rn(pt, __fmul_rn(sg, xv[ci][tap]));
          }
          acc = __fadd_rn(acc, pt);
        }
        float v = __fadd_rn(acc, c1b[co]);
        float t = bn_t32(v, g1[co], bt1[co]);
        outw |= ((u32)(unsigned char)tsign(t)) << (8*j);
      }
      *reinterpret_cast<u32*>(&s1[pixbase + co4]) = outw;
    }
  }
}

// ---------------------------------------------------------------------------
// MFMA ternary bconv (+ in-register 2x2 pool) + f32 bn + ternary int8 out.
// (unchanged from r9)
// ---------------------------------------------------------------------------
template<int CIN, int COUT, int H, int W, int POOL>
__global__ __launch_bounds__(256) void bconv_m(
    const s8* __restrict__ A, const s8* __restrict__ WF,
    const float* __restrict__ g, const float* __restrict__ bt,
    s8* __restrict__ O){
  constexpr int KK = CIN/32, CG = COUT/32, CGB = 2;
  constexpr int XT = (W >= 16) ? 16 : 8;
  constexpr int YT = 32 / XT;
  constexpr int TPR = W / XT;
  constexpr int TROWS = H / YT;
  constexpr int HO = POOL ? H/2 : H, WO = POOL ? W/2 : W;
  int tid = threadIdx.x, lane = tid & 63, wv = tid >> 6;
  int wid = blockIdx.x*4 + wv;
  int cb = wid % (CG/CGB); int mt = wid / (CG/CGB);
  int tx = mt % TPR; int r0 = mt / TPR;
  int ty = r0 % TROWS; int n = r0 / TROWS;
  int y0 = ty*YT, x0 = tx*XT;
  int p = lane & 31;
  int py = p / XT, px = p % XT;
  int y = y0 + py, x = x0 + px;
  int kh = lane >> 5;
  const s8* An = A + (size_t)n*H*W*CIN;

  i32x16 acc0 = {0,0,0,0,0,0,0,0,0,0,0,0,0,0,0,0};
  i32x16 acc1 = {0,0,0,0,0,0,0,0,0,0,0,0,0,0,0,0};

  #pragma unroll
  for (int tap = 0; tap < 9; tap++){
    int dy = tap/3 - 1, dx = tap%3 - 1;
    int sy = y + dy, sx = x + dx;
    bool ok = ((unsigned)sy < (unsigned)H) && ((unsigned)sx < (unsigned)W);
    const s8* ap = An + ((size_t)sy*W + sx)*CIN + kh*16;
    const s8* wp = WF + (((size_t)tap*KK)*CG + (size_t)cb*CGB)*1024 + lane*16;
    #pragma unroll
    for (int kk = 0; kk < KK; kk++){
      i32x4 av = {0,0,0,0};
      if (ok) av = *reinterpret_cast<const i32x4*>(ap + kk*32);
      const s8* wk = wp + (size_t)kk*CG*1024;
      i32x4 b0 = *reinterpret_cast<const i32x4*>(wk);
      i32x4 b1 = *reinterpret_cast<const i32x4*>(wk + 1024);
      acc0 = __builtin_amdgcn_mfma_i32_32x32x32_i8(av, b0, acc0, 0, 0, 0);
      acc1 = __builtin_amdgcn_mfma_i32_32x32x32_i8(av, b1, acc1, 0, 0, 0);
    }
  }

  #pragma unroll
  for (int cgb = 0; cgb < CGB; cgb++){
    i32x16 acc = cgb ? acc1 : acc0;
    int co = (cb*CGB + cgb)*32 + (lane & 31);
    float gg = g[co], bb = bt[co];
    if (POOL){
      constexpr int RY = (XT == 16) ? 8 : 4;
      #pragma unroll
      for (int q = 0; q < 4; q++){
        int rr = (q&1)*2 + (q>>1)*((XT == 16) ? 4 : 8);
        int z = max(max(acc[rr], acc[rr+1]), max(acc[rr+RY], acc[rr+RY+1]));
        int pb = (rr&3) + 8*(rr>>2) + 4*kh;
        int yy = y0 + pb/XT, xx2 = x0 + pb%XT;
        int oy = yy >> 1, ox = xx2 >> 1;
        float t = bn_t32((float)z, gg, bb);
        O[(((size_t)n*HO + oy)*WO + ox)*COUT + co] = tsign(t);
      }
    } else {
      #pragma unroll
      for (int rr = 0; rr < 16; rr++){
        int pb = (rr&3) + 8*(rr>>2) + 4*kh;
        int yy = y0 + pb/XT, xx2 = x0 + pb%XT;
        float t = bn_t32((float)acc[rr], gg, bb);
        O[(((size_t)n*H + yy)*W + xx2)*COUT + co] = tsign(t);
      }
    }
  }
}

// s6 int8 NHWC [128][4][4][512] -> ternary bitplanes [n][kw=px*16+cw][2]
__global__ void repack6_k(const s8* __restrict__ s6, u32* __restrict__ Op){
  int idx = blockIdx.x*256 + threadIdx.x;   // 128*256
  if (idx >= 128*256) return;
  int n = idx >> 8, kw = idx & 255;
  int px = kw >> 4, cw = kw & 15;
  const s8* p = s6 + ((size_t)n*16 + px)*512 + cw*32;
  u32 a = 0, s = 0;
  for (int j = 0; j < 32; j++){
    s8 v = p[j];
    a |= (u32)(v != 0) << j;
    s |= (u32)(v > 0) << j;
  }
  Op[((size_t)n*256 + kw)*2]   = a;
  Op[((size_t)n*256 + kw)*2+1] = s;
}

// ---------------------------------------------------------------------------
// Ternary FC + f32 bn + ternary ballot (bitplanes). Unchanged.
// ---------------------------------------------------------------------------
template<int KW>
__global__ __launch_bounds__(256) void fcb_k(
    const u32* __restrict__ A, const u32* __restrict__ Wp,
    const float* __restrict__ fb,
    const float* __restrict__ g, const float* __restrict__ bt,
    u32* __restrict__ Op){
  int tid = threadIdx.x; int lane = tid & 63; int wv = tid >> 6;
  int wid = blockIdx.x*4 + wv;          // 128*16 waves
  int og = wid & 15; int n = wid >> 4;
  int o = og*64 + lane;
  const uint2* a = reinterpret_cast<const uint2*>(&A[(size_t)n*KW*2]);
  int z = 0;
  #pragma unroll 8
  for (int kw = 0; kw < KW; kw++){
    uint2 av = a[kw];
    uint2 wv_ = reinterpret_cast<const uint2*>(Wp)[kw*1024 + o];
    u32 v = av.x & wv_.x;
    u32 d = v & (av.y ^ wv_.y);
    z += __popc(v) - 2*__popc(d);
  }
  float vv = __fadd_rn((float)z, fb[o]);
  float t = bn_t32(vv, g[o], bt[o]);
  u64 mP = __ballot(t > 0.f);
  u64 mN = __ballot(t < 0.f);
  if (lane == 0){
    int ob = (n*32 + og*2)*2;
    Op[ob]   = (u32)(mP | mN);
    Op[ob+1] = (u32)mP;
    Op[ob+2] = (u32)((mP | mN) >> 32);
    Op[ob+3] = (u32)(mP >> 32);
  }
}

// fc3 (10 outputs) + bn + log_softmax -> f32 out [128][10]
__global__ void fc3_k(const u32* __restrict__ A, const u32* __restrict__ Wp,
                      const float* __restrict__ fb,
                      const float* __restrict__ g,
                      const float* __restrict__ bt,
                      float* __restrict__ out){
  int n = blockIdx.x; int lane = threadIdx.x;   // blockDim = 64
  __shared__ double ls[10];
  double t = 0.0;
  if (lane < 10){
    const uint2* a = reinterpret_cast<const uint2*>(&A[(size_t)n*32*2]);
    int z = 0;
    for (int kw = 0; kw < 32; kw++){
      uint2 av = a[kw];
      uint2 wv_ = reinterpret_cast<const uint2*>(Wp)[kw*10 + lane];
      u32 v = av.x & wv_.x;
      u32 d = v & (av.y ^ wv_.y);
      z += __popc(v) - 2*__popc(d);
    }
    float vv = __fadd_rn((float)z, fb[lane]);
    float tf = bn_t32(vv, g[lane], bt[lane]);
    t = (double)tf;
    ls[lane] = t;
  }
  __syncthreads();
  if (lane < 10){
    double m = -1e300;
    for (int j = 0; j < 10; j++) m = fmax(m, ls[j]);
    double sum = 0.0;
    for (int j = 0; j < 10; j++) sum += exp(ls[j] - m);
    double r = t - m - log(sum);
    out[n*10 + lane] = (float)r;
  }
}

extern "C" void kernel_launch(void* const* d_in, const int* in_sizes, int n_in,
                              void* d_out, int out_size, void* d_ws, size_t ws_size,
                              hipStream_t stream){
  auto f = [&](int i){ return (const float*)d_in[i]; };
  const float *x  = f(0),  *w1 = f(1),  *c1b = f(2),
    *w2 = f(3),  *w3 = f(4),  *w4 = f(5),  *w5 = f(6),  *w6 = f(7),
    *fw1 = f(8), *fb1 = f(9), *fw2 = f(10), *fb2 = f(11),
    *fw3 = f(12), *fb3 = f(13),
    *g1 = f(14), *bt1 = f(15), *g2 = f(16), *bt2 = f(17),
    *g3 = f(18), *bt3 = f(19), *g4 = f(20), *bt4 = f(21),
    *g5 = f(22), *bt5 = f(23), *g6 = f(24), *bt6 = f(25),
    *gf1 = f(26), *btf1 = f(27), *gf2 = f(28), *btf2 = f(29),
    *gf3 = f(30), *btf3 = f(31);

  char* base = (char*)d_ws;
  size_t off = 0;
  auto alloc = [&](size_t bytes){ char* p = base + off; off += (bytes + 255) & ~(size_t)255; return p; };
  s8* poolA = (s8*)alloc(128ull*32*32*128);       // s1 / s3 / s5
  s8* poolB = (s8*)alloc(128ull*16*16*128);       // s2 / s4 / s6
  s8 *s1 = poolA, *s3 = poolA, *s5 = poolA;
  s8 *s2 = poolB, *s4 = poolB, *s6 = poolB;
  s8 *wf2 = (s8*)alloc(9ull*128*128), *wf3 = (s8*)alloc(9ull*128*256),
     *wf4 = (s8*)alloc(9ull*256*256), *wf5 = (s8*)alloc(9ull*256*512),
     *wf6 = (s8*)alloc(9ull*512*512);
  u32 *wp1  = (u32*)alloc(5760);                  // bitplanes + ctl + flag
  u32 *fw1p = (u32*)alloc(2ull*256*1024*4), *fw2p = (u32*)alloc(2ull*32*1024*4),
      *fw3p = (u32*)alloc(2ull*32*10*4);
  u32 *s6p  = (u32*)alloc(2ull*128*256*4);
  u32 *sf1  = (u32*)alloc(2ull*128*32*4), *sf2 = (u32*)alloc(2ull*128*32*4);

  // weight packing
  pack_w1_k<<<1, 64, 0, stream>>>(w1, wp1);
  pack_wfrag_k<<<128, 256, 0, stream>>>(w2, wf2, 128, 128);
  pack_wfrag_k<<<256, 256, 0, stream>>>(w3, wf3, 128, 256);
  pack_wfrag_k<<<256, 256, 0, stream>>>(w4, wf4, 256, 256);
  pack_wfrag_k<<<512, 256, 0, stream>>>(w5, wf5, 256, 512);
  pack_wfrag_k<<<512, 256, 0, stream>>>(w6, wf6, 512, 512);
  pack_fc1_2k<<<1024, 256, 0, stream>>>(fw1, fw1p);
  pack_fc2_k<<<1024, 256, 0, stream>>>(fw2, fw2p, 1024, 1024);
  pack_fc2_k<<<10, 256, 0, stream>>>(fw3, fw3p, 1024, 10);

  // network
  conv1_k<<<1024, 256, 0, stream>>>(x, wp1, c1b, g1, bt1, s1);
  bconv_m<128,128,32,32,1><<<2048, 256, 0, stream>>>(s1, wf2, g2, bt2, s2);
  bconv_m<128,256,16,16,0><<<1024, 256, 0, stream>>>(s2, wf3, g3, bt3, s3);
  bconv_m<256,256,16,16,1><<<1024, 256, 0, stream>>>(s3, wf4, g4, bt4, s4);
  bconv_m<256,512, 8, 8,0><<< 512, 256, 0, stream>>>(s4, wf5, g5, bt5, s5);
  bconv_m<512,512, 8, 8,1><<< 512, 256, 0, stream>>>(s5, wf6, g6, bt6, s6);
  repack6_k<<<128, 256, 0, stream>>>(s6, s6p);
  fcb_k<256><<<(128*16)/4, 256, 0, stream>>>(s6p, fw1p, fb1, gf1, btf1, sf1);
  fcb_k<32><<<(128*16)/4,  256, 0, stream>>>(sf1, fw2p, fb2, gf2, btf2, sf2);
  fc3_k<<<128, 64, 0, stream>>>(sf2, fw3p, fb3, gf3, btf3, (float*)d_out);
}

// Round 11
// 352.198 us; speedup vs baseline: 4.4058x; 1.0478x over previous
//
#include <hip/hip_runtime.h>
#include <hip/hip_bf16.h>

using u32 = unsigned int;
using u64 = unsigned long long;
using s8  = signed char;
typedef int i32x4  __attribute__((ext_vector_type(4)));
typedef int i32x16 __attribute__((ext_vector_type(16)));

__device__ __forceinline__ s8 tsign(float t){
  return (t > 0.f) ? (s8)1 : ((t < 0.f) ? (s8)-1 : (s8)0);
}
// threshold with precomputed scale: t = fl(fl(z*sc)+b) — identical roundings
__device__ __forceinline__ float bn_ts(float z, float sc, float b){
  return __fadd_rn(__fmul_rn(z, sc), b);
}

// ---------------------------------------------------------------------------
// per-channel scale precompute: sc[c] = fl(g[c] * rs), rs as in rounds 6-10
// layout: sc1@0(128) sc2@128 sc3@256 sc4@512 sc5@768 sc6@1280
//         scf1@1792 scf2@2816 scf3@3840 ; total 3850
// ---------------------------------------------------------------------------
__global__ void scales_k(const float* g1, const float* g2, const float* g3,
                         const float* g4, const float* g5, const float* g6,
                         const float* gf1, const float* gf2, const float* gf3,
                         float* sc){
  int i = blockIdx.x*256 + threadIdx.x;
  const float rs = __fdiv_rn(1.0f, __fsqrt_rn((float)(1.0 + 1e-5)));
  float v;
  if      (i < 128)  v = g1[i];
  else if (i < 256)  v = g2[i-128];
  else if (i < 512)  v = g3[i-256];
  else if (i < 768)  v = g4[i-512];
  else if (i < 1280) v = g5[i-768];
  else if (i < 1792) v = g6[i-1280];
  else if (i < 2816) v = gf1[i-1792];
  else if (i < 3840) v = gf2[i-2816];
  else if (i < 3850) v = gf3[i-3840];
  else return;
  sc[i] = __fmul_rn(v, rs);
}

// ---------------------------------------------------------------------------
// Merged conv-weight MFMA-fragment pack (5 layers, one dispatch).
// ---------------------------------------------------------------------------
__global__ __launch_bounds__(256) void pack_wfrag_all_k(
    const float* __restrict__ w2, const float* __restrict__ w3,
    const float* __restrict__ w4, const float* __restrict__ w5,
    const float* __restrict__ w6,
    s8* __restrict__ wf2, s8* __restrict__ wf3, s8* __restrict__ wf4,
    s8* __restrict__ wf5, s8* __restrict__ wf6){
  int b = blockIdx.x;
  const float* w; s8* wf; int CIN, COUT, co;
  if      (b < 128) { w=w2; wf=wf2; CIN=128; COUT=128; co=b; }
  else if (b < 384) { w=w3; wf=wf3; CIN=128; COUT=256; co=b-128; }
  else if (b < 640) { w=w4; wf=wf4; CIN=256; COUT=256; co=b-384; }
  else if (b < 1152){ w=w5; wf=wf5; CIN=256; COUT=512; co=b-640; }
  else              { w=w6; wf=wf6; CIN=512; COUT=512; co=b-1152; }
  __shared__ s8 sb[4608];
  int nf = CIN*9;
  const float* wb = w + (size_t)co*nf;
  for (int i = threadIdx.x; i < nf; i += 256){
    float v = wb[i];
    sb[i] = (v > 0.f) ? (s8)1 : ((v < 0.f) ? (s8)-1 : (s8)0);
  }
  __syncthreads();
  int KK = CIN >> 5, CG = COUT >> 5;
  int cg = co >> 5, llo = co & 31;
  for (int i = threadIdx.x; i < nf; i += 256){
    int tap = i / CIN, k = i - tap*CIN;
    s8 v = sb[k*9 + tap];
    size_t dst = ((((size_t)tap*KK + (k>>5))*CG + cg)*64
                  + (llo + ((k>>4)&1)*32))*16 + (k&15);
    wf[dst] = v;
  }
}

// ---------------------------------------------------------------------------
// w1 pack v4: bitplanes [co*2..], ONE ctl word per co at [256+co] (27 bits,
// field 3*tap: bit0 = sign(w0)==sign(w1), bit1 = w0<0, bit2 = w2<0),
// global any-zero flag at [384].
// ---------------------------------------------------------------------------
__global__ void pack_w1_k(const float* __restrict__ w1, u32* __restrict__ wp1){
  int lane = threadIdx.x;                 // one wave of 64
  bool hz = false;
  for (int h = 0; h < 2; h++){
    int co = h*64 + lane;
    u32 a = 0, s = 0, ctlw = 0;
    for (int tap = 0; tap < 9; tap++){
      float v0 = w1[(co*3 + 0)*9 + tap];
      float v1 = w1[(co*3 + 1)*9 + tap];
      float v2 = w1[(co*3 + 2)*9 + tap];
      int b0 = tap*3;
      a |= ((v0 != 0.f) ? 1u : 0u) << b0;     s |= ((v0 > 0.f) ? 1u : 0u) << b0;
      a |= ((v1 != 0.f) ? 1u : 0u) << (b0+1); s |= ((v1 > 0.f) ? 1u : 0u) << (b0+1);
      a |= ((v2 != 0.f) ? 1u : 0u) << (b0+2); s |= ((v2 > 0.f) ? 1u : 0u) << (b0+2);
      hz |= (v0 == 0.f) || (v1 == 0.f) || (v2 == 0.f);
      u32 f = (((v0 > 0.f) == (v1 > 0.f)) ? 1u : 0u)
            | ((v0 < 0.f) ? 2u : 0u)
            | ((v2 < 0.f) ? 4u : 0u);
      ctlw |= f << b0;
    }
    wp1[co*2]   = a;
    wp1[co*2+1] = s;
    wp1[256 + co] = ctlw;
  }
  u64 m = __ballot(hz);
  if (lane == 0) wp1[384] = (m != 0ull) ? 1u : 0u;
}

// FC weight pack (ternary bitplanes), merged fw2+fw3: grid 1034
__global__ __launch_bounds__(256) void pack_fcB_k(const float* __restrict__ wa,
    const float* __restrict__ wb3, u32* __restrict__ wpa, u32* __restrict__ wpb){
  int b = blockIdx.x;
  const float* w; u32* wp; int COUT, co;
  if (b < 1024){ w = wa; wp = wpa; COUT = 1024; co = b; }
  else         { w = wb3; wp = wpb; COUT = 10;  co = b-1024; }
  __shared__ unsigned char sb[1024];
  const float* wbp = w + (size_t)co*1024;
  for (int i = threadIdx.x; i < 1024; i += 256){
    float v = wbp[i];
    sb[i] = (unsigned char)(((v != 0.f) ? 2u : 0u) | ((v > 0.f) ? 1u : 0u));
  }
  __syncthreads();
  for (int kw = threadIdx.x; kw < 32; kw += 256){
    u32 a = 0, s = 0;
    for (int j = 0; j < 32; j++){
      unsigned char bch = sb[kw*32 + j];
      a |= (u32)(bch >> 1) << j;
      s |= (u32)(bch & 1u) << j;
    }
    size_t o = ((size_t)kw*COUT + co)*2;
    wp[o] = a; wp[o+1] = s;
  }
}

// fc1 pack, K permuted to [px][cw] word order: k = c*16 + px, kw = px*16+cw
__global__ __launch_bounds__(256) void pack_fc1_2k(const float* __restrict__ w,
    u32* __restrict__ wp){
  int co = blockIdx.x;                        // 1024 blocks
  __shared__ unsigned char sb[8192];
  const float* wb = w + (size_t)co*8192;
  for (int i = threadIdx.x; i < 8192; i += 256){
    float v = wb[i];
    sb[i] = (unsigned char)(((v != 0.f) ? 2u : 0u) | ((v > 0.f) ? 1u : 0u));
  }
  __syncthreads();
  int kw = threadIdx.x;                       // 256 words exactly
  int px = kw >> 4, cw = kw & 15;
  u32 a = 0, s = 0;
  for (int j = 0; j < 32; j++){
    unsigned char bch = sb[(cw*32 + j)*16 + px];
    a |= (u32)(bch >> 1) << j;
    s |= (u32)(bch & 1u) << j;
  }
  size_t o = ((size_t)kw*1024 + co)*2;
  wp[o] = a; wp[o+1] = s;
}

// ---------------------------------------------------------------------------
// conv1 v4: lanes = 64 pixels, couts = wave-uniform loop; one ctl word per co;
// precomputed scale. Bit-exact vs the verified r6 chain.
// ---------------------------------------------------------------------------
__global__ __launch_bounds__(256) void conv1_k(
    const float* __restrict__ x, const u32* __restrict__ wp1,
    const float* __restrict__ c1b,
    const float* __restrict__ sc1, const float* __restrict__ bt1,
    s8* __restrict__ s1){
  int tid = threadIdx.x, lane = tid & 63, wv = tid >> 6;
  int wid = blockIdx.x*4 + wv;          // 4096 waves: [n(128)][chunk(16)][coh(2)]
  int coh = wid & 1;
  int chunk = (wid >> 1) & 15;
  int n = wid >> 5;
  int py = lane >> 5, px = lane & 31;
  int y = chunk*2 + py;
  const float* xb = x + (size_t)n*3*1024;

  float xv[3][9];
  #pragma unroll
  for (int ci = 0; ci < 3; ci++)
    #pragma unroll
    for (int tap = 0; tap < 9; tap++){
      int yy = y + tap/3 - 1, xx = px + tap%3 - 1;
      bool ok = ((unsigned)yy < 32u) && ((unsigned)xx < 32u);
      xv[ci][tap] = ok ? xb[(ci*32 + yy)*32 + xx] : 0.f;
    }
  float pc0[9], pc1[9];
  #pragma unroll
  for (int tap = 0; tap < 9; tap++){
    pc0[tap] = __fadd_rn(xv[0][tap], xv[1][tap]);
    pc1[tap] = __fadd_rn(xv[0][tap], -xv[1][tap]);
  }

  size_t pixbase = (((size_t)n*1024) + y*32 + px)*128 + coh*64;
  bool fallback = (wp1[384] != 0u);

  if (!fallback){
    for (int co4 = 0; co4 < 64; co4 += 4){
      u32 outw = 0;
      #pragma unroll
      for (int j = 0; j < 4; j++){
        int co = coh*64 + co4 + j;
        u32 ctlw = wp1[256 + co];            // wave-uniform, one load
        float acc = 0.f;
        #pragma unroll
        for (int tap = 0; tap < 9; tap++){
          u32 f = ctlw >> (3*tap);
          float s01 = (f & 1u) ? pc0[tap] : pc1[tap];
          s01 = __uint_as_float(__float_as_uint(s01) ^ ((f & 2u) << 30));
          float t2 = __uint_as_float(__float_as_uint(xv[2][tap]) ^ ((f & 4u) << 29));
          acc = __fadd_rn(acc, __fadd_rn(s01, t2));
        }
        float v = __fadd_rn(acc, c1b[co]);
        float t = bn_ts(v, sc1[co], bt1[co]);
        outw |= ((u32)(unsigned char)tsign(t)) << (8*j);
      }
      *reinterpret_cast<u32*>(&s1[pixbase + co4]) = outw;
    }
  } else {
    for (int co4 = 0; co4 < 64; co4 += 4){
      u32 outw = 0;
      #pragma unroll
      for (int j = 0; j < 4; j++){
        int co = coh*64 + co4 + j;
        u32 wA = wp1[co*2], wS = wp1[co*2+1];
        float acc = 0.f;
        #pragma unroll
        for (int tap = 0; tap < 9; tap++){
          float pt = 0.f;
          #pragma unroll
          for (int ci = 0; ci < 3; ci++){
            int bit = tap*3 + ci;
            float sg = ((wA >> bit) & 1u) ? (((wS >> bit) & 1u) ? 1.f : -1.f) : 0.f;
            pt = __fadd_rn(pt, __fmul_rn(sg, xv[ci][tap]));
          }
          acc = __fadd_rn(acc, pt);
        }
        float v = __fadd_rn(acc, c1b[co]);
        float t = bn_ts(v, sc1[co], bt1[co]);
        outw |= ((u32)(unsigned char)tsign(t)) << (8*j);
      }
      *reinterpret_cast<u32*>(&s1[pixbase + co4]) = outw;
    }
  }
}

// ---------------------------------------------------------------------------
// MFMA ternary bconv (+ in-register 2x2 pool) + threshold.
// BITOUT=1 (block 6): emit fc1-layout ternary bitplanes via ballot, skip s8 out.
// ---------------------------------------------------------------------------
template<int CIN, int COUT, int H, int W, int POOL, int BITOUT>
__global__ __launch_bounds__(256) void bconv_m(
    const s8* __restrict__ A, const s8* __restrict__ WF,
    const float* __restrict__ sc, const float* __restrict__ bt,
    s8* __restrict__ O, u32* __restrict__ OB){
  constexpr int KK = CIN/32, CG = COUT/32, CGB = 2;
  constexpr int XT = (W >= 16) ? 16 : 8;
  constexpr int YT = 32 / XT;
  constexpr int TPR = W / XT;
  constexpr int TROWS = H / YT;
  constexpr int HO = POOL ? H/2 : H, WO = POOL ? W/2 : W;
  int tid = threadIdx.x, lane = tid & 63, wv = tid >> 6;
  int wid = blockIdx.x*4 + wv;
  int cb = wid % (CG/CGB); int mt = wid / (CG/CGB);
  int tx = mt % TPR; int r0 = mt / TPR;
  int ty = r0 % TROWS; int n = r0 / TROWS;
  int y0 = ty*YT, x0 = tx*XT;
  int p = lane & 31;
  int py = p / XT, px = p % XT;
  int y = y0 + py, x = x0 + px;
  int kh = lane >> 5;
  const s8* An = A + (size_t)n*H*W*CIN;

  i32x16 acc0 = {0,0,0,0,0,0,0,0,0,0,0,0,0,0,0,0};
  i32x16 acc1 = {0,0,0,0,0,0,0,0,0,0,0,0,0,0,0,0};

  #pragma unroll
  for (int tap = 0; tap < 9; tap++){
    int dy = tap/3 - 1, dx = tap%3 - 1;
    int sy = y + dy, sx = x + dx;
    bool ok = ((unsigned)sy < (unsigned)H) && ((unsigned)sx < (unsigned)W);
    const s8* ap = An + ((size_t)sy*W + sx)*CIN + kh*16;
    const s8* wp = WF + (((size_t)tap*KK)*CG + (size_t)cb*CGB)*1024 + lane*16;
    #pragma unroll
    for (int kk = 0; kk < KK; kk++){
      i32x4 av = {0,0,0,0};
      if (ok) av = *reinterpret_cast<const i32x4*>(ap + kk*32);
      const s8* wk = wp + (size_t)kk*CG*1024;
      i32x4 b0 = *reinterpret_cast<const i32x4*>(wk);
      i32x4 b1 = *reinterpret_cast<const i32x4*>(wk + 1024);
      acc0 = __builtin_amdgcn_mfma_i32_32x32x32_i8(av, b0, acc0, 0, 0, 0);
      acc1 = __builtin_amdgcn_mfma_i32_32x32x32_i8(av, b1, acc1, 0, 0, 0);
    }
  }

  #pragma unroll
  for (int cgb = 0; cgb < CGB; cgb++){
    i32x16 acc = cgb ? acc1 : acc0;
    int co = (cb*CGB + cgb)*32 + (lane & 31);
    float ss = sc[co], bb = bt[co];
    if (POOL){
      constexpr int RY = (XT == 16) ? 8 : 4;
      #pragma unroll
      for (int q = 0; q < 4; q++){
        int rr = (q&1)*2 + (q>>1)*((XT == 16) ? 4 : 8);
        int z = max(max(acc[rr], acc[rr+1]), max(acc[rr+RY], acc[rr+RY+1]));
        float t = bn_ts((float)z, ss, bb);
        if (!BITOUT){
          int pb = (rr&3) + 8*(rr>>2) + 4*kh;
          int yy = y0 + pb/XT, xx2 = x0 + pb%XT;
          int oy = yy >> 1, ox = xx2 >> 1;
          O[(((size_t)n*HO + oy)*WO + ox)*COUT + co] = tsign(t);
        } else {
          // block 6 only: H=W=8, XT=8. lo 32 lanes = pixel(kh=0), hi = pixel(kh=1)
          u64 mP = __ballot(t > 0.f);
          u64 mN = __ballot(t < 0.f);
          if (lane == 0){
            u64 mA = mP | mN;
            int cw = cb*CGB + cgb;
            int pb0 = (rr&3) + 8*(rr>>2);
            int yy0 = y0 + pb0/XT, xx0 = x0 + pb0%XT;
            int p0 = (yy0>>1)*4 + (xx0>>1);
            int pb1 = pb0 + 4;
            int yy1 = y0 + pb1/XT, xx1 = x0 + pb1%XT;
            int p1 = (yy1>>1)*4 + (xx1>>1);
            size_t o0 = ((size_t)n*256 + p0*16 + cw)*2;
            size_t o1 = ((size_t)n*256 + p1*16 + cw)*2;
            OB[o0]   = (u32)mA;       OB[o0+1] = (u32)mP;
            OB[o1]   = (u32)(mA>>32); OB[o1+1] = (u32)(mP>>32);
          }
        }
      }
    } else {
      #pragma unroll
      for (int rr = 0; rr < 16; rr++){
        int pb = (rr&3) + 8*(rr>>2) + 4*kh;
        int yy = y0 + pb/XT, xx2 = x0 + pb%XT;
        float t = bn_ts((float)acc[rr], ss, bb);
        O[(((size_t)n*H + yy)*W + xx2)*COUT + co] = tsign(t);
      }
    }
  }
}

// ---------------------------------------------------------------------------
// Ternary FC + threshold + ternary ballot (bitplanes).
// ---------------------------------------------------------------------------
template<int KW>
__global__ __launch_bounds__(256) void fcb_k(
    const u32* __restrict__ A, const u32* __restrict__ Wp,
    const float* __restrict__ fb,
    const float* __restrict__ sc, const float* __restrict__ bt,
    u32* __restrict__ Op){
  int tid = threadIdx.x; int lane = tid & 63; int wv = tid >> 6;
  int wid = blockIdx.x*4 + wv;          // 128*16 waves
  int og = wid & 15; int n = wid >> 4;
  int o = og*64 + lane;
  const uint2* a = reinterpret_cast<const uint2*>(&A[(size_t)n*KW*2]);
  int z = 0;
  #pragma unroll 8
  for (int kw = 0; kw < KW; kw++){
    uint2 av = a[kw];
    uint2 wv_ = reinterpret_cast<const uint2*>(Wp)[kw*1024 + o];
    u32 v = av.x & wv_.x;
    u32 d = v & (av.y ^ wv_.y);
    z += __popc(v) - 2*__popc(d);
  }
  float vv = __fadd_rn((float)z, fb[o]);
  float t = bn_ts(vv, sc[o], bt[o]);
  u64 mP = __ballot(t > 0.f);
  u64 mN = __ballot(t < 0.f);
  if (lane == 0){
    int ob = (n*32 + og*2)*2;
    Op[ob]   = (u32)(mP | mN);
    Op[ob+1] = (u32)mP;
    Op[ob+2] = (u32)((mP | mN) >> 32);
    Op[ob+3] = (u32)(mP >> 32);
  }
}

// fc3 (10 outputs) + bn + log_softmax -> f32 out [128][10]
__global__ void fc3_k(const u32* __restrict__ A, const u32* __restrict__ Wp,
                      const float* __restrict__ fb,
                      const float* __restrict__ sc,
                      const float* __restrict__ bt,
                      float* __restrict__ out){
  int n = blockIdx.x; int lane = threadIdx.x;   // blockDim = 64
  __shared__ double ls[10];
  double t = 0.0;
  if (lane < 10){
    const uint2* a = reinterpret_cast<const uint2*>(&A[(size_t)n*32*2]);
    int z = 0;
    for (int kw = 0; kw < 32; kw++){
      uint2 av = a[kw];
      uint2 wv_ = reinterpret_cast<const uint2*>(Wp)[kw*10 + lane];
      u32 v = av.x & wv_.x;
      u32 d = v & (av.y ^ wv_.y);
      z += __popc(v) - 2*__popc(d);
    }
    float vv = __fadd_rn((float)z, fb[lane]);
    float tf = bn_ts(vv, sc[lane], bt[lane]);
    t = (double)tf;
    ls[lane] = t;
  }
  __syncthreads();
  if (lane < 10){
    double m = -1e300;
    for (int j = 0; j < 10; j++) m = fmax(m, ls[j]);
    double sum = 0.0;
    for (int j = 0; j < 10; j++) sum += exp(ls[j] - m);
    double r = t - m - log(sum);
    out[n*10 + lane] = (float)r;
  }
}

extern "C" void kernel_launch(void* const* d_in, const int* in_sizes, int n_in,
                              void* d_out, int out_size, void* d_ws, size_t ws_size,
                              hipStream_t stream){
  auto f = [&](int i){ return (const float*)d_in[i]; };
  const float *x  = f(0),  *w1 = f(1),  *c1b = f(2),
    *w2 = f(3),  *w3 = f(4),  *w4 = f(5),  *w5 = f(6),  *w6 = f(7),
    *fw1 = f(8), *fb1 = f(9), *fw2 = f(10), *fb2 = f(11),
    *fw3 = f(12), *fb3 = f(13),
    *g1 = f(14), *bt1 = f(15), *g2 = f(16), *bt2 = f(17),
    *g3 = f(18), *bt3 = f(19), *g4 = f(20), *bt4 = f(21),
    *g5 = f(22), *bt5 = f(23), *g6 = f(24), *bt6 = f(25),
    *gf1 = f(26), *btf1 = f(27), *gf2 = f(28), *btf2 = f(29),
    *gf3 = f(30), *btf3 = f(31);

  char* base = (char*)d_ws;
  size_t off = 0;
  auto alloc = [&](size_t bytes){ char* p = base + off; off += (bytes + 255) & ~(size_t)255; return p; };
  s8* poolA = (s8*)alloc(128ull*32*32*128);       // s1 / s3 / s5
  s8* poolB = (s8*)alloc(128ull*16*16*128);       // s2 / s4
  s8 *s1 = poolA, *s3 = poolA, *s5 = poolA;
  s8 *s2 = poolB, *s4 = poolB;
  s8 *wf2 = (s8*)alloc(9ull*128*128), *wf3 = (s8*)alloc(9ull*128*256),
     *wf4 = (s8*)alloc(9ull*256*256), *wf5 = (s8*)alloc(9ull*256*512),
     *wf6 = (s8*)alloc(9ull*512*512);
  u32 *wp1  = (u32*)alloc(385*4);                 // bitplanes + ctl + flag
  float* scb = (float*)alloc(3850*4);             // per-channel scales
  u32 *fw1p = (u32*)alloc(2ull*256*1024*4), *fw2p = (u32*)alloc(2ull*32*1024*4),
      *fw3p = (u32*)alloc(2ull*32*10*4);
  u32 *s6p  = (u32*)alloc(2ull*128*256*4);
  u32 *sf1  = (u32*)alloc(2ull*128*32*4), *sf2 = (u32*)alloc(2ull*128*32*4);

  float *sc1 = scb, *sc2 = scb+128, *sc3 = scb+256, *sc4 = scb+512,
        *sc5 = scb+768, *sc6 = scb+1280, *scf1 = scb+1792, *scf2 = scb+2816,
        *scf3 = scb+3840;

  // packing / precompute
  scales_k<<<16, 256, 0, stream>>>(g1,g2,g3,g4,g5,g6,gf1,gf2,gf3, scb);
  pack_w1_k<<<1, 64, 0, stream>>>(w1, wp1);
  pack_wfrag_all_k<<<1664, 256, 0, stream>>>(w2,w3,w4,w5,w6, wf2,wf3,wf4,wf5,wf6);
  pack_fc1_2k<<<1024, 256, 0, stream>>>(fw1, fw1p);
  pack_fcB_k<<<1034, 256, 0, stream>>>(fw2, fw3, fw2p, fw3p);

  // network
  conv1_k<<<1024, 256, 0, stream>>>(x, wp1, c1b, sc1, bt1, s1);
  bconv_m<128,128,32,32,1,0><<<2048, 256, 0, stream>>>(s1, wf2, sc2, bt2, s2, nullptr);
  bconv_m<128,256,16,16,0,0><<<1024, 256, 0, stream>>>(s2, wf3, sc3, bt3, s3, nullptr);
  bconv_m<256,256,16,16,1,0><<<1024, 256, 0, stream>>>(s3, wf4, sc4, bt4, s4, nullptr);
  bconv_m<256,512, 8, 8,0,0><<< 512, 256, 0, stream>>>(s4, wf5, sc5, bt5, s5, nullptr);
  bconv_m<512,512, 8, 8,1,1><<< 512, 256, 0, stream>>>(s5, wf6, sc6, bt6, nullptr, s6p);
  fcb_k<256><<<(128*16)/4, 256, 0, stream>>>(s6p, fw1p, fb1, scf1, btf1, sf1);
  fcb_k<32><<<(128*16)/4,  256, 0, stream>>>(sf1, fw2p, fb2, scf2, btf2, sf2);
  fc3_k<<<128, 64, 0, stream>>>(sf2, fw3p, fb3, scf3, btf3, (float*)d_out);
}